// Round 1
// baseline (1299.779 us; speedup 1.0000x reference)
//
#include <hip/hip_runtime.h>
#include <hip/hip_bf16.h>

typedef __hip_bfloat16 bf16;

constexpr int N = 25000;
constexpr int E = 250000;
constexpr size_t NB = (size_t)N * 128;            // 3,200,000

constexpr size_t al256(size_t x) { return (x + 255) / 256 * 256; }

// Workspace layout (float element offsets). Total ~14.7 MB.
constexpr size_t OFF_WE   = 0;                    // W_e  [384x128] f32
constexpr size_t OFF_WM1  = OFF_WE + 49152;       // W_m1 [128x256] f32
constexpr size_t OFF_WM2  = OFF_WM1 + 32768;      // W_m2 [256x128] f32
constexpr size_t OFF_BNS  = OFF_WM2 + 32768;      // 256 f32 BN col sums
constexpr size_t OFF_BNQ  = OFF_BNS + 256;        // 256 f32 BN col sumsq
constexpr size_t OFF_FLAG = OFF_BNQ + 256;        // dtype flag (int in slot 0)
constexpr size_t OFF_XN   = OFF_FLAG + 256;       // N f32 ||x|| per row
constexpr size_t OFF_DEG  = al256(OFF_XN + N);    // int[N]   in-degree counts
constexpr size_t OFF_OFFS = al256(OFF_DEG + N);   // int[N+1] CSR row offsets
constexpr size_t OFF_CUR  = al256(OFF_OFFS + N + 1); // int[N] scatter cursors
constexpr size_t OFF_LIST = al256(OFF_CUR + N);   // int[E]  edge ids by dest
constexpr size_t OFF_A    = al256(OFF_LIST + E);
// Region A: NB f32 slots (= 2*NB bf16), reused twice:
//   phase 1: XA [0,NB) bf16 | XB [NB,2NB) bf16
//   phase 2: H1 [0,2NB) bf16 (N x 256) overlays XA|XB
constexpr size_t WS_FLOATS = OFF_A + NB;          // ~3.67M f32 = 14.7 MB

// ---------------- dtype-agnostic access ----------------

__device__ __forceinline__ float b2f(bf16 v) { return __bfloat162float(v); }

__device__ __forceinline__ float ldf(const void* p, size_t i, int bf) {
    return bf ? b2f(((const bf16*)p)[i]) : ((const float*)p)[i];
}
__device__ __forceinline__ void stf(void* p, size_t i, float v, int bf) {
    if (bf) ((bf16*)p)[i] = __float2bfloat16(v);
    else    ((float*)p)[i] = v;
}
__device__ __forceinline__ float lds_scalar(const void* p, int bf) {
    if (!bf) return *(const float*)p;
    float v = b2f(*(const bf16*)p);
    float a = fabsf(v);
    return (a >= 0.0009765625f && a <= 1024.0f) ? v : *(const float*)p;
}
__device__ __forceinline__ int get_flag(const float* ws) {
    return *(const int*)(ws + OFF_FLAG);
}
__device__ __forceinline__ void* e_base(void* d_out, int bf) {
    return bf ? (void*)((bf16*)d_out + NB) : (void*)((float*)d_out + NB);
}

// Block-wide sum for blockDim.x == 128 (2 waves).
__device__ __forceinline__ float block_sum(float v, float* red) {
    #pragma unroll
    for (int off = 32; off; off >>= 1) v += __shfl_xor(v, off, 64);
    int w = threadIdx.x >> 6;
    if ((threadIdx.x & 63) == 0) red[w] = v;
    __syncthreads();
    float r = red[0] + red[1];
    __syncthreads();
    return r;
}

// ---------------- kernels ----------------

// Detect element dtype of x (N(0,1) data).
__global__ void k_detect(const unsigned short* __restrict__ xu, float* __restrict__ ws) {
    __shared__ int cnt;
    if (threadIdx.x == 0) cnt = 0;
    __syncthreads();
    int c = 0;
    for (int i = threadIdx.x; i < 512; i += 256) {
        unsigned e = (xu[i] >> 7) & 0xFFu;
        if (e >= 110u && e <= 135u) c++;
    }
    atomicAdd(&cnt, c);
    __syncthreads();
    if (threadIdx.x == 0) *(int*)(ws + OFF_FLAG) = (cnt >= 460) ? 1 : 0;
}

// Convert weights to f32 in ws; zero BN accumulators and degree counts.
__global__ void k_init(float* __restrict__ ws, const void* __restrict__ W_e,
                       const void* __restrict__ W_m1, const void* __restrict__ W_m2) {
    int bf = get_flag(ws);
    size_t gid = (size_t)blockIdx.x * blockDim.x + threadIdx.x;
    size_t stride = (size_t)gridDim.x * blockDim.x;
    for (size_t i = gid; i < 49152; i += stride) ws[OFF_WE + i] = ldf(W_e, i, bf);
    for (size_t i = gid; i < 32768; i += stride) ws[OFF_WM1 + i] = ldf(W_m1, i, bf);
    for (size_t i = gid; i < 32768; i += stride) ws[OFF_WM2 + i] = ldf(W_m2, i, bf);
    for (size_t i = gid; i < 512; i += stride) ws[OFF_BNS + i] = 0.0f;
    int* deg = (int*)(ws + OFF_DEG);
    for (size_t i = gid; i < N; i += stride) deg[i] = 0;
}

// Per node: xa = x@We[0:128] + b_e, xb = x@We[128:256] (bf16 in region A), ||x||.
__global__ __launch_bounds__(128) void k_node_pre(const void* __restrict__ x,
                                                  const void* __restrict__ b_e,
                                                  float* __restrict__ ws) {
    int bf = get_flag(ws);
    int n = blockIdx.x, tid = threadIdx.x;
    __shared__ float xs[128];
    __shared__ float red[2];
    float xv = ldf(x, (size_t)n * 128 + tid, bf);
    xs[tid] = xv;
    __syncthreads();
    const float* W1 = ws + OFF_WE + tid;
    const float* W2 = ws + OFF_WE + 16384 + tid;
    float a1 = ldf(b_e, tid, bf), a2 = 0.f;
    #pragma unroll 8
    for (int k = 0; k < 128; ++k) {
        float xk = xs[k];
        a1 = fmaf(xk, W1[k * 128], a1);
        a2 = fmaf(xk, W2[k * 128], a2);
    }
    bf16* XA = (bf16*)(ws + OFF_A);
    XA[(size_t)n * 128 + tid] = __float2bfloat16(a1);
    XA[NB + (size_t)n * 128 + tid] = __float2bfloat16(a2);
    float s = block_sum(xv * xv, red);
    if (tid == 0) ws[OFF_XN + n] = sqrtf(s);
}

// Per edge: Linear(cat) -> ReLU -> LN -> +edge_attr -> e. Also counts in-degree.
__global__ __launch_bounds__(128) void k_edge1(const void* __restrict__ ea,
                                               const int* __restrict__ ei,
                                               const void* __restrict__ g_e,
                                               const void* __restrict__ be_e,
                                               float* __restrict__ ws,
                                               void* __restrict__ d_out) {
    int bf = get_flag(ws);
    void* eo = e_base(d_out, bf);
    int j = blockIdx.x, tid = threadIdx.x;
    int r = ei[j], cd = ei[E + j];
    if (tid == 0) atomicAdd((int*)(ws + OFF_DEG) + cd, 1);
    __shared__ float eas[128];
    __shared__ float red[2];
    float eav = ldf(ea, (size_t)j * 128 + tid, bf);
    eas[tid] = eav;
    __syncthreads();
    const bf16* XA = (const bf16*)(ws + OFF_A);
    float acc = b2f(XA[(size_t)r * 128 + tid]) + b2f(XA[NB + (size_t)cd * 128 + tid]);
    const float* W3 = ws + OFF_WE + 32768 + tid;
    #pragma unroll 8
    for (int k = 0; k < 128; ++k) acc = fmaf(eas[k], W3[k * 128], acc);
    acc = fmaxf(acc, 0.f);
    float mu = block_sum(acc, red) * (1.f / 128.f);
    float dv = acc - mu;
    float var = block_sum(dv * dv, red) * (1.f / 128.f);
    float ev = dv * rsqrtf(var + 1e-5f) * ldf(g_e, tid, bf) + ldf(be_e, tid, bf) + eav;
    stf(eo, (size_t)j * 128 + tid, ev, bf);
}

// Exclusive scan of degree counts -> CSR offsets + scatter cursors. 1 block.
__global__ __launch_bounds__(256) void k_scan(float* __restrict__ ws) {
    const int* deg = (const int*)(ws + OFF_DEG);
    int* offs = (int*)(ws + OFF_OFFS);
    int* cur  = (int*)(ws + OFF_CUR);
    __shared__ int sums[256];
    __shared__ int carry[257];
    int t = threadIdx.x;
    const int chunk = (N + 255) / 256;            // 98
    int lo = t * chunk, hi = lo + chunk < N ? lo + chunk : N;
    int s = 0;
    for (int i = lo; i < hi; ++i) s += deg[i];
    sums[t] = s;
    __syncthreads();
    if (t == 0) {
        int acc = 0;
        #pragma unroll 4
        for (int i = 0; i < 256; ++i) { carry[i] = acc; acc += sums[i]; }
        carry[256] = acc;
    }
    __syncthreads();
    int acc = carry[t];
    for (int i = lo; i < hi; ++i) { offs[i] = acc; cur[i] = acc; acc += deg[i]; }
    if (t == 0) offs[N] = carry[256];
}

// Scatter edge ids into CSR list by destination.
__global__ void k_scatter(const int* __restrict__ ei, float* __restrict__ ws) {
    int j = blockIdx.x * blockDim.x + threadIdx.x;
    if (j >= E) return;
    int cd = ei[E + j];
    int pos = atomicAdd((int*)(ws + OFF_CUR) + cd, 1);
    ((int*)(ws + OFF_LIST))[pos] = j;
}

// Per node: gather incident edges, softmax-aggregate in registers (fixed-shift
// exp, softmax is shift invariant and 0 <= msg*t <~ 22), then fuse
// out = agg + x and h1 = out@W_m1 + b_m1 -> H1 bf16 (overlays XA|XB).
__global__ __launch_bounds__(256) void k_agg(const void* __restrict__ x,
                                             const int* __restrict__ ei,
                                             const void* __restrict__ t_p,
                                             const void* __restrict__ b_m1,
                                             void* __restrict__ d_out,
                                             float* __restrict__ ws) {
    int bf = get_flag(ws);
    const void* e_in = e_base(d_out, bf);
    int n = blockIdx.x, tid = threadIdx.x;
    int c = tid & 127, half = tid >> 7;
    const int* offs = (const int*)(ws + OFF_OFFS);
    const int* list = (const int*)(ws + OFF_LIST);
    int s0 = offs[n], s1 = offs[n + 1];
    float t = lds_scalar(t_p, bf);
    float den = 0.f, num = 0.f;
    for (int i = s0 + half; i < s1; i += 2) {
        int j = list[i];
        int r = ei[j];
        float ev = ldf(e_in, (size_t)j * 128 + c, bf);
        float msg = fmaxf(ldf(x, (size_t)r * 128 + c, bf) + ev, 0.f) + 1e-7f;
        float ex = expf(msg * t - 15.0f);
        den += ex;
        num = fmaf(msg, ex, num);
    }
    __shared__ float dsh[256];
    __shared__ float nsh[256];
    __shared__ float outs[128];
    dsh[tid] = den;
    nsh[tid] = num;
    __syncthreads();
    if (tid < 128) {
        float dn = dsh[tid] + dsh[tid + 128];
        float nm = nsh[tid] + nsh[tid + 128];
        float ag = dn > 0.f ? nm / dn : 0.f;
        outs[tid] = ag + ldf(x, (size_t)n * 128 + tid, bf);
    }
    __syncthreads();
    const float* WM1 = ws + OFF_WM1 + tid;
    float acc = ldf(b_m1, tid, bf);
    #pragma unroll 8
    for (int k = 0; k < 128; ++k) acc = fmaf(outs[k], WM1[k * 256], acc);
    ((bf16*)(ws + OFF_A))[(size_t)n * 256 + tid] = __float2bfloat16(acc);
}

// BatchNorm statistics: column sums / sumsq of h1 over N rows.
__global__ __launch_bounds__(256) void k_bnstats(float* __restrict__ ws) {
    int t = threadIdx.x;
    const bf16* H1 = (const bf16*)(ws + OFF_A);
    float s = 0.f, q = 0.f;
    for (int r = blockIdx.x; r < N; r += gridDim.x) {
        float v = b2f(H1[(size_t)r * 256 + t]);
        s += v;
        q = fmaf(v, v, q);
    }
    atomicAdd(&ws[OFF_BNS + t], s);
    atomicAdd(&ws[OFF_BNQ + t], q);
}

// Per node: BN+ReLU, h = .@W_m2 + b_m2, MessageNorm, residual + LayerNorm.
__global__ __launch_bounds__(128) void k_node_post(const void* __restrict__ x,
                                                   const void* __restrict__ g_bn,
                                                   const void* __restrict__ b_bn,
                                                   const void* __restrict__ b_m2,
                                                   const void* __restrict__ scale_p,
                                                   const void* __restrict__ g_n,
                                                   const void* __restrict__ b_n,
                                                   float* __restrict__ ws,
                                                   void* __restrict__ x_out) {
    int bf = get_flag(ws);
    int n = blockIdx.x, tid = threadIdx.x;
    __shared__ float hbn[256];
    __shared__ float red[2];
    const bf16* H1 = (const bf16*)(ws + OFF_A);
    const float inv_n = 1.f / (float)N;
    for (int k = tid; k < 256; k += 128) {
        float v = b2f(H1[(size_t)n * 256 + k]);
        float mu = ws[OFF_BNS + k] * inv_n;
        float var = ws[OFF_BNQ + k] * inv_n - mu * mu;
        float hb = (v - mu) * rsqrtf(fmaxf(var, 0.f) + 1e-5f) * ldf(g_bn, k, bf) + ldf(b_bn, k, bf);
        hbn[k] = fmaxf(hb, 0.f);
    }
    __syncthreads();
    const float* WM2 = ws + OFF_WM2 + tid;
    float acc = ldf(b_m2, tid, bf);
    #pragma unroll 8
    for (int k = 0; k < 256; ++k) acc = fmaf(hbn[k], WM2[k * 128], acc);
    float hn2 = block_sum(acc * acc, red);
    float h = acc / fmaxf(sqrtf(hn2), 1e-12f) * ws[OFF_XN + n] * lds_scalar(scale_p, bf);
    float y = ldf(x, (size_t)n * 128 + tid, bf) + h;
    float mu = block_sum(y, red) * (1.f / 128.f);
    float dv = y - mu;
    float var = block_sum(dv * dv, red) * (1.f / 128.f);
    float o = dv * rsqrtf(var + 1e-5f) * ldf(g_n, tid, bf) + ldf(b_n, tid, bf);
    stf(x_out, (size_t)n * 128 + tid, o, bf);
}

// ---------------- launcher ----------------

extern "C" void kernel_launch(void* const* d_in, const int* in_sizes, int n_in,
                              void* d_out, int out_size, void* d_ws, size_t ws_size,
                              hipStream_t stream) {
    const void* x    = d_in[0];
    const void* ea   = d_in[1];
    const int*  ei   = (const int*)d_in[2];
    const void* W_e  = d_in[3];
    const void* b_e  = d_in[4];
    const void* g_e  = d_in[5];
    const void* be_e = d_in[6];
    const void* t_p  = d_in[7];
    const void* W_m1 = d_in[8];
    const void* b_m1 = d_in[9];
    const void* g_bn = d_in[10];
    const void* b_bn = d_in[11];
    const void* W_m2 = d_in[12];
    const void* b_m2 = d_in[13];
    const void* scl  = d_in[14];
    const void* g_n  = d_in[15];
    const void* b_n  = d_in[16];

    float* ws = (float*)d_ws;

    k_detect<<<1, 256, 0, stream>>>((const unsigned short*)x, ws);
    k_init<<<512, 256, 0, stream>>>(ws, W_e, W_m1, W_m2);
    k_node_pre<<<N, 128, 0, stream>>>(x, b_e, ws);
    k_edge1<<<E, 128, 0, stream>>>(ea, ei, g_e, be_e, ws, d_out);
    k_scan<<<1, 256, 0, stream>>>(ws);
    k_scatter<<<(E + 255) / 256, 256, 0, stream>>>(ei, ws);
    k_agg<<<N, 256, 0, stream>>>(x, ei, t_p, b_m1, d_out, ws);
    k_bnstats<<<256, 256, 0, stream>>>(ws);
    k_node_post<<<N, 128, 0, stream>>>(x, g_bn, b_bn, b_m2, scl, g_n, b_n, ws, d_out);
}

// Round 2
// 847.852 us; speedup vs baseline: 1.5330x; 1.5330x over previous
//
#include <hip/hip_runtime.h>
#include <hip/hip_bf16.h>

typedef __hip_bfloat16 bf16;
typedef __attribute__((ext_vector_type(8))) short short8v;   // 8 bf16 (4 VGPRs)
typedef __attribute__((ext_vector_type(4))) float float4v;   // MFMA acc

constexpr int N = 25000;
constexpr int E = 250000;
constexpr size_t NB = (size_t)N * 128;            // 3,200,000

constexpr size_t al256(size_t x) { return (x + 255) / 256 * 256; }

// Workspace layout (float element offsets). Total ~14.8 MB.
constexpr size_t OFF_WE   = 0;                    // W_e  [384x128] f32 (only rows 0..255 used)
constexpr size_t OFF_WM1  = OFF_WE + 49152;       // W_m1 [128x256] f32
constexpr size_t OFF_WM2  = OFF_WM1 + 32768;      // W_m2 [256x128] f32
constexpr size_t OFF_BNS  = OFF_WM2 + 32768;      // 256 f32 BN col sums
constexpr size_t OFF_BNQ  = OFF_BNS + 256;        // 256 f32 BN col sumsq
constexpr size_t OFF_FLAG = OFF_BNQ + 256;        // dtype flag (int in slot 0)
constexpr size_t OFF_XN   = OFF_FLAG + 256;       // N f32 ||x|| per row
constexpr size_t OFF_WB   = al256(OFF_XN + N);    // W3 bf16 fragment-packed: 16384 bf16 = 8192 f32
constexpr size_t OFF_DEG  = al256(OFF_WB + 8192); // int[N]   in-degree counts
constexpr size_t OFF_OFFS = al256(OFF_DEG + N);   // int[N+1] CSR row offsets
constexpr size_t OFF_CUR  = al256(OFF_OFFS + N + 1); // int[N] scatter cursors
constexpr size_t OFF_LIST = al256(OFF_CUR + N);   // int[E]  edge ids by dest
constexpr size_t OFF_A    = al256(OFF_LIST + E);
// Region A: NB f32 slots (= 2*NB bf16), reused twice:
//   phase 1: XA [0,NB) bf16 | XB [NB,2NB) bf16
//   phase 2: H1 [0,2NB) bf16 (N x 256) overlays XA|XB
constexpr size_t WS_FLOATS = OFF_A + NB;

// ---------------- dtype-agnostic access ----------------

__device__ __forceinline__ float b2f(bf16 v) { return __bfloat162float(v); }
__device__ __forceinline__ short f2bs(float f) {
    bf16 h = __float2bfloat16(f);
    return *reinterpret_cast<short*>(&h);
}

__device__ __forceinline__ float ldf(const void* p, size_t i, int bf) {
    return bf ? b2f(((const bf16*)p)[i]) : ((const float*)p)[i];
}
__device__ __forceinline__ void stf(void* p, size_t i, float v, int bf) {
    if (bf) ((bf16*)p)[i] = __float2bfloat16(v);
    else    ((float*)p)[i] = v;
}
__device__ __forceinline__ float lds_scalar(const void* p, int bf) {
    if (!bf) return *(const float*)p;
    float v = b2f(*(const bf16*)p);
    float a = fabsf(v);
    return (a >= 0.0009765625f && a <= 1024.0f) ? v : *(const float*)p;
}
__device__ __forceinline__ int get_flag(const float* ws) {
    return *(const int*)(ws + OFF_FLAG);
}
__device__ __forceinline__ void* e_base(void* d_out, int bf) {
    return bf ? (void*)((bf16*)d_out + NB) : (void*)((float*)d_out + NB);
}

// Block-wide sum for blockDim.x == 128 (2 waves).
__device__ __forceinline__ float block_sum(float v, float* red) {
    #pragma unroll
    for (int off = 32; off; off >>= 1) v += __shfl_xor(v, off, 64);
    int w = threadIdx.x >> 6;
    if ((threadIdx.x & 63) == 0) red[w] = v;
    __syncthreads();
    float r = red[0] + red[1];
    __syncthreads();
    return r;
}

// ---------------- kernels ----------------

// Detect element dtype of x (N(0,1) data).
__global__ void k_detect(const unsigned short* __restrict__ xu, float* __restrict__ ws) {
    __shared__ int cnt;
    if (threadIdx.x == 0) cnt = 0;
    __syncthreads();
    int c = 0;
    for (int i = threadIdx.x; i < 512; i += 256) {
        unsigned e = (xu[i] >> 7) & 0xFFu;
        if (e >= 110u && e <= 135u) c++;
    }
    atomicAdd(&cnt, c);
    __syncthreads();
    if (threadIdx.x == 0) *(int*)(ws + OFF_FLAG) = (cnt >= 460) ? 1 : 0;
}

// Convert weights to f32 in ws; pack W3 (rows 256..383 of W_e) into bf16
// MFMA-fragment order; zero BN accumulators and degree counts.
// WB flat idx t: i=t&7, l=(t>>3)&63, n=(t>>9)&7, s=t>>12
//   -> k = s*32 + (l>>4)*8 + i, c = n*16 + (l&15).
__global__ void k_init(float* __restrict__ ws, const void* __restrict__ W_e,
                       const void* __restrict__ W_m1, const void* __restrict__ W_m2) {
    int bf = get_flag(ws);
    size_t gid = (size_t)blockIdx.x * blockDim.x + threadIdx.x;
    size_t stride = (size_t)gridDim.x * blockDim.x;
    for (size_t i = gid; i < 32768; i += stride) ws[OFF_WE + i] = ldf(W_e, i, bf);
    for (size_t i = gid; i < 32768; i += stride) ws[OFF_WM1 + i] = ldf(W_m1, i, bf);
    for (size_t i = gid; i < 32768; i += stride) ws[OFF_WM2 + i] = ldf(W_m2, i, bf);
    for (size_t i = gid; i < 512; i += stride) ws[OFF_BNS + i] = 0.0f;
    short* WB = (short*)(ws + OFF_WB);
    for (size_t t = gid; t < 16384; t += stride) {
        int i = t & 7, l = (t >> 3) & 63, n = (t >> 9) & 7, s = t >> 12;
        int k = s * 32 + (l >> 4) * 8 + i;
        int c = n * 16 + (l & 15);
        WB[t] = f2bs(ldf(W_e, (size_t)(256 + k) * 128 + c, bf));
    }
    int* deg = (int*)(ws + OFF_DEG);
    for (size_t i = gid; i < N; i += stride) deg[i] = 0;
}

// Per node: xa = x@We[0:128] + b_e, xb = x@We[128:256] (bf16 in region A), ||x||.
__global__ __launch_bounds__(128) void k_node_pre(const void* __restrict__ x,
                                                  const void* __restrict__ b_e,
                                                  float* __restrict__ ws) {
    int bf = get_flag(ws);
    int n = blockIdx.x, tid = threadIdx.x;
    __shared__ float xs[128];
    __shared__ float red[2];
    float xv = ldf(x, (size_t)n * 128 + tid, bf);
    xs[tid] = xv;
    __syncthreads();
    const float* W1 = ws + OFF_WE + tid;
    const float* W2 = ws + OFF_WE + 16384 + tid;
    float a1 = ldf(b_e, tid, bf), a2 = 0.f;
    #pragma unroll 8
    for (int k = 0; k < 128; ++k) {
        float xk = xs[k];
        a1 = fmaf(xk, W1[k * 128], a1);
        a2 = fmaf(xk, W2[k * 128], a2);
    }
    bf16* XA = (bf16*)(ws + OFF_A);
    XA[(size_t)n * 128 + tid] = __float2bfloat16(a1);
    XA[NB + (size_t)n * 128 + tid] = __float2bfloat16(a2);
    float s = block_sum(xv * xv, red);
    if (tid == 0) ws[OFF_XN + n] = sqrtf(s);
}

// Per-edge MLP via MFMA. Each wave: 16 edges x 128 out channels.
//   pre = XA[r] + XB[cd] + ea @ W3   (XA has b_e folded in)
//   e   = LN(relu(pre)) * g + b + ea
// MFMA 16x16x32 bf16: A row = lane&15 (edge), k = (lane>>4)*8+i;
// B from WB (frag-packed); C/D col = lane&15, row(edge) = (lane>>4)*4+reg.
__global__ __launch_bounds__(256) void k_edge1_mfma(const void* __restrict__ ea,
                                                    const int* __restrict__ ei,
                                                    const void* __restrict__ g_e,
                                                    const void* __restrict__ be_e,
                                                    float* __restrict__ ws,
                                                    void* __restrict__ d_out) {
    int bf = get_flag(ws);
    void* eo = e_base(d_out, bf);
    int l = threadIdx.x & 63;
    int wv = threadIdx.x >> 6;
    int e0w = blockIdx.x * 64 + wv * 16;          // first edge of this wave
    if (e0w >= E) return;                         // whole-wave exit, no barriers used

    // in-degree count: one lane per edge
    if (l < 16) {
        int j = e0w + l;
        if (j < E) atomicAdd((int*)(ws + OFF_DEG) + ei[E + j], 1);
    }

    int row = l & 15, grp = l >> 4;

    // ---- GEMM: acc[n] += A(ea rows) * B(W3 cols) ----
    int ja = e0w + row;
    int jac = ja < E ? ja : E - 1;
    const short8v* WB = (const short8v*)(ws + OFF_WB);
    float4v acc[8];
    #pragma unroll
    for (int n = 0; n < 8; ++n) acc[n] = (float4v){0.f, 0.f, 0.f, 0.f};

    #pragma unroll
    for (int s = 0; s < 4; ++s) {
        short8v af;
        if (bf) {
            af = ((const short8v*)ea)[(size_t)jac * 16 + s * 4 + grp];
        } else {
            const float* er = (const float*)ea + (size_t)jac * 128 + s * 32 + grp * 8;
            float4v lo = *(const float4v*)er;
            float4v hi = *(const float4v*)(er + 4);
            af[0] = f2bs(lo[0]); af[1] = f2bs(lo[1]); af[2] = f2bs(lo[2]); af[3] = f2bs(lo[3]);
            af[4] = f2bs(hi[0]); af[5] = f2bs(hi[1]); af[6] = f2bs(hi[2]); af[7] = f2bs(hi[3]);
        }
        #pragma unroll
        for (int n = 0; n < 8; ++n) {
            short8v bfr = WB[(s * 8 + n) * 64 + l];
            acc[n] = __builtin_amdgcn_mfma_f32_16x16x32_bf16(af, bfr, acc[n], 0, 0, 0);
        }
    }

    // ---- epilogue: gather, relu, LN (16-lane group per edge), store ----
    int jr[4], rr[4], cc[4];
    #pragma unroll
    for (int reg = 0; reg < 4; ++reg) {
        int j = e0w + grp * 4 + reg;
        int jc = j < E ? j : E - 1;
        jr[reg] = j;
        rr[reg] = ei[jc];
        cc[reg] = ei[E + jc];
    }
    const bf16* XA = (const bf16*)(ws + OFF_A);
    float p[8][4];
    #pragma unroll
    for (int n = 0; n < 8; ++n) {
        int col = n * 16 + row;
        #pragma unroll
        for (int reg = 0; reg < 4; ++reg) {
            float v = acc[n][reg]
                    + b2f(XA[(size_t)rr[reg] * 128 + col])
                    + b2f(XA[NB + (size_t)cc[reg] * 128 + col]);
            p[n][reg] = fmaxf(v, 0.f);
        }
    }
    #pragma unroll
    for (int reg = 0; reg < 4; ++reg) {
        float s1 = 0.f;
        #pragma unroll
        for (int n = 0; n < 8; ++n) s1 += p[n][reg];
        #pragma unroll
        for (int off = 1; off < 16; off <<= 1) s1 += __shfl_xor(s1, off, 64);
        float mu = s1 * (1.f / 128.f);
        float s2 = 0.f;
        #pragma unroll
        for (int n = 0; n < 8; ++n) { float d = p[n][reg] - mu; s2 = fmaf(d, d, s2); }
        #pragma unroll
        for (int off = 1; off < 16; off <<= 1) s2 += __shfl_xor(s2, off, 64);
        float rstd = rsqrtf(s2 * (1.f / 128.f) + 1e-5f);
        if (jr[reg] < E) {
            size_t jb = (size_t)jr[reg] * 128;
            #pragma unroll
            for (int n = 0; n < 8; ++n) {
                int col = n * 16 + row;
                float ev = (p[n][reg] - mu) * rstd * ldf(g_e, col, bf)
                         + ldf(be_e, col, bf) + ldf(ea, jb + col, bf);
                stf(eo, jb + col, ev, bf);
            }
        }
    }
}

// Exclusive scan of degree counts -> CSR offsets + scatter cursors. 1 block.
__global__ __launch_bounds__(256) void k_scan(float* __restrict__ ws) {
    const int* deg = (const int*)(ws + OFF_DEG);
    int* offs = (int*)(ws + OFF_OFFS);
    int* cur  = (int*)(ws + OFF_CUR);
    __shared__ int sums[256];
    __shared__ int carry[257];
    int t = threadIdx.x;
    const int chunk = (N + 255) / 256;            // 98
    int lo = t * chunk, hi = lo + chunk < N ? lo + chunk : N;
    int s = 0;
    for (int i = lo; i < hi; ++i) s += deg[i];
    sums[t] = s;
    __syncthreads();
    if (t == 0) {
        int acc = 0;
        #pragma unroll 4
        for (int i = 0; i < 256; ++i) { carry[i] = acc; acc += sums[i]; }
        carry[256] = acc;
    }
    __syncthreads();
    int acc = carry[t];
    for (int i = lo; i < hi; ++i) { offs[i] = acc; cur[i] = acc; acc += deg[i]; }
    if (t == 0) offs[N] = carry[256];
}

// Scatter edge ids into CSR list by destination.
__global__ void k_scatter(const int* __restrict__ ei, float* __restrict__ ws) {
    int j = blockIdx.x * blockDim.x + threadIdx.x;
    if (j >= E) return;
    int cd = ei[E + j];
    int pos = atomicAdd((int*)(ws + OFF_CUR) + cd, 1);
    ((int*)(ws + OFF_LIST))[pos] = j;
}

// Per node: gather incident edges, softmax-aggregate in registers (fixed-shift
// exp, softmax is shift invariant and 0 <= msg*t <~ 22), then fuse
// out = agg + x and h1 = out@W_m1 + b_m1 -> H1 bf16 (overlays XA|XB).
__global__ __launch_bounds__(256) void k_agg(const void* __restrict__ x,
                                             const int* __restrict__ ei,
                                             const void* __restrict__ t_p,
                                             const void* __restrict__ b_m1,
                                             void* __restrict__ d_out,
                                             float* __restrict__ ws) {
    int bf = get_flag(ws);
    const void* e_in = e_base(d_out, bf);
    int n = blockIdx.x, tid = threadIdx.x;
    int c = tid & 127, half = tid >> 7;
    const int* offs = (const int*)(ws + OFF_OFFS);
    const int* list = (const int*)(ws + OFF_LIST);
    int s0 = offs[n], s1 = offs[n + 1];
    float t = lds_scalar(t_p, bf);
    float den = 0.f, num = 0.f;
    for (int i = s0 + half; i < s1; i += 2) {
        int j = list[i];
        int r = ei[j];
        float ev = ldf(e_in, (size_t)j * 128 + c, bf);
        float msg = fmaxf(ldf(x, (size_t)r * 128 + c, bf) + ev, 0.f) + 1e-7f;
        float ex = expf(msg * t - 15.0f);
        den += ex;
        num = fmaf(msg, ex, num);
    }
    __shared__ float dsh[256];
    __shared__ float nsh[256];
    __shared__ float outs[128];
    dsh[tid] = den;
    nsh[tid] = num;
    __syncthreads();
    if (tid < 128) {
        float dn = dsh[tid] + dsh[tid + 128];
        float nm = nsh[tid] + nsh[tid + 128];
        float ag = dn > 0.f ? nm / dn : 0.f;
        outs[tid] = ag + ldf(x, (size_t)n * 128 + tid, bf);
    }
    __syncthreads();
    const float* WM1 = ws + OFF_WM1 + tid;
    float acc = ldf(b_m1, tid, bf);
    #pragma unroll 8
    for (int k = 0; k < 128; ++k) acc = fmaf(outs[k], WM1[k * 256], acc);
    ((bf16*)(ws + OFF_A))[(size_t)n * 256 + tid] = __float2bfloat16(acc);
}

// BatchNorm statistics: column sums / sumsq of h1 over N rows.
__global__ __launch_bounds__(256) void k_bnstats(float* __restrict__ ws) {
    int t = threadIdx.x;
    const bf16* H1 = (const bf16*)(ws + OFF_A);
    float s = 0.f, q = 0.f;
    for (int r = blockIdx.x; r < N; r += gridDim.x) {
        float v = b2f(H1[(size_t)r * 256 + t]);
        s += v;
        q = fmaf(v, v, q);
    }
    atomicAdd(&ws[OFF_BNS + t], s);
    atomicAdd(&ws[OFF_BNQ + t], q);
}

// Per node: BN+ReLU, h = .@W_m2 + b_m2, MessageNorm, residual + LayerNorm.
__global__ __launch_bounds__(128) void k_node_post(const void* __restrict__ x,
                                                   const void* __restrict__ g_bn,
                                                   const void* __restrict__ b_bn,
                                                   const void* __restrict__ b_m2,
                                                   const void* __restrict__ scale_p,
                                                   const void* __restrict__ g_n,
                                                   const void* __restrict__ b_n,
                                                   float* __restrict__ ws,
                                                   void* __restrict__ x_out) {
    int bf = get_flag(ws);
    int n = blockIdx.x, tid = threadIdx.x;
    __shared__ float hbn[256];
    __shared__ float red[2];
    const bf16* H1 = (const bf16*)(ws + OFF_A);
    const float inv_n = 1.f / (float)N;
    for (int k = tid; k < 256; k += 128) {
        float v = b2f(H1[(size_t)n * 256 + k]);
        float mu = ws[OFF_BNS + k] * inv_n;
        float var = ws[OFF_BNQ + k] * inv_n - mu * mu;
        float hb = (v - mu) * rsqrtf(fmaxf(var, 0.f) + 1e-5f) * ldf(g_bn, k, bf) + ldf(b_bn, k, bf);
        hbn[k] = fmaxf(hb, 0.f);
    }
    __syncthreads();
    const float* WM2 = ws + OFF_WM2 + tid;
    float acc = ldf(b_m2, tid, bf);
    #pragma unroll 8
    for (int k = 0; k < 256; ++k) acc = fmaf(hbn[k], WM2[k * 128], acc);
    float hn2 = block_sum(acc * acc, red);
    float h = acc / fmaxf(sqrtf(hn2), 1e-12f) * ws[OFF_XN + n] * lds_scalar(scale_p, bf);
    float y = ldf(x, (size_t)n * 128 + tid, bf) + h;
    float mu = block_sum(y, red) * (1.f / 128.f);
    float dv = y - mu;
    float var = block_sum(dv * dv, red) * (1.f / 128.f);
    float o = dv * rsqrtf(var + 1e-5f) * ldf(g_n, tid, bf) + ldf(b_n, tid, bf);
    stf(x_out, (size_t)n * 128 + tid, o, bf);
}

// ---------------- launcher ----------------

extern "C" void kernel_launch(void* const* d_in, const int* in_sizes, int n_in,
                              void* d_out, int out_size, void* d_ws, size_t ws_size,
                              hipStream_t stream) {
    const void* x    = d_in[0];
    const void* ea   = d_in[1];
    const int*  ei   = (const int*)d_in[2];
    const void* W_e  = d_in[3];
    const void* b_e  = d_in[4];
    const void* g_e  = d_in[5];
    const void* be_e = d_in[6];
    const void* t_p  = d_in[7];
    const void* W_m1 = d_in[8];
    const void* b_m1 = d_in[9];
    const void* g_bn = d_in[10];
    const void* b_bn = d_in[11];
    const void* W_m2 = d_in[12];
    const void* b_m2 = d_in[13];
    const void* scl  = d_in[14];
    const void* g_n  = d_in[15];
    const void* b_n  = d_in[16];

    float* ws = (float*)d_ws;

    k_detect<<<1, 256, 0, stream>>>((const unsigned short*)x, ws);
    k_init<<<512, 256, 0, stream>>>(ws, W_e, W_m1, W_m2);
    k_node_pre<<<N, 128, 0, stream>>>(x, b_e, ws);
    k_edge1_mfma<<<(E + 63) / 64, 256, 0, stream>>>(ea, ei, g_e, be_e, ws, d_out);
    k_scan<<<1, 256, 0, stream>>>(ws);
    k_scatter<<<(E + 255) / 256, 256, 0, stream>>>(ei, ws);
    k_agg<<<N, 256, 0, stream>>>(x, ei, t_p, b_m1, d_out, ws);
    k_bnstats<<<256, 256, 0, stream>>>(ws);
    k_node_post<<<N, 128, 0, stream>>>(x, g_bn, b_bn, b_m2, scl, g_n, b_n, ws, d_out);
}

// Round 4
// 622.107 us; speedup vs baseline: 2.0893x; 1.3629x over previous
//
#include <hip/hip_runtime.h>
#include <hip/hip_bf16.h>

typedef __hip_bfloat16 bf16;
typedef __attribute__((ext_vector_type(8))) short short8v;   // 8 bf16 (4 VGPRs)
typedef __attribute__((ext_vector_type(4))) float float4v;   // MFMA acc

constexpr int N = 25000;
constexpr int E = 250000;
constexpr size_t NB = (size_t)N * 128;            // 3,200,000
constexpr int NBLK = (N + 63) / 64;               // 391 node-tiles of 64

constexpr size_t al256(size_t x) { return (x + 255) / 256 * 256; }

// Workspace layout (float element offsets). Total ~21 MB.
constexpr size_t OFF_BNS  = 0;                    // 256 f32 BN col sums
constexpr size_t OFF_BNQ  = OFF_BNS + 256;        // 256 f32 BN col sumsq
constexpr size_t OFF_FLAG = OFF_BNQ + 256;        // dtype flag (int in slot 0)
constexpr size_t OFF_XN   = OFF_FLAG + 256;       // N f32 ||x|| per row
constexpr size_t OFF_WB   = al256(OFF_XN + N);    // W3   bf16 frag-packed 16384 (8192 f32)
constexpr size_t OFF_WP   = OFF_WB + 8192;        // W1|W2 bf16 frag-packed 32768 (16384 f32)
constexpr size_t OFF_WM1P = OFF_WP + 16384;       // W_m1 bf16 frag-packed 32768
constexpr size_t OFF_WM2P = OFF_WM1P + 16384;     // W_m2 bf16 frag-packed 32768
constexpr size_t OFF_DEG  = al256(OFF_WM2P + 16384); // int[N] in-degree
constexpr size_t OFF_OFFS = al256(OFF_DEG + N);   // int[N+1] CSR offsets
constexpr size_t OFF_CUR  = al256(OFF_OFFS + N + 1); // int[N] cursors
constexpr size_t OFF_LIST = al256(OFF_CUR + N);   // int[E] edge ids by dest
constexpr size_t OFF_OUT  = al256(OFF_LIST + E);  // out = agg+x, N*128 bf16 (NB/2 f32)
constexpr size_t OFF_A    = al256(OFF_OUT + NB / 2);
// Region A: NB f32 slots (= 2*NB bf16), reused twice:
//   phase 1: XA [0,NB) bf16 | XB [NB,2NB) bf16
//   phase 2: H1 [0,2NB) bf16 (N x 256) overlays XA|XB
constexpr size_t WS_FLOATS = OFF_A + NB;

// ---------------- dtype-agnostic access ----------------

__device__ __forceinline__ float b2f(bf16 v) { return __bfloat162float(v); }
__device__ __forceinline__ short f2bs(float f) {
    bf16 h = __float2bfloat16(f);
    return *reinterpret_cast<short*>(&h);
}
__device__ __forceinline__ float bs2f(short s) {
    bf16 h;
    *reinterpret_cast<short*>(&h) = s;
    return b2f(h);
}

__device__ __forceinline__ float ldf(const void* p, size_t i, int bf) {
    return bf ? b2f(((const bf16*)p)[i]) : ((const float*)p)[i];
}
__device__ __forceinline__ void stf(void* p, size_t i, float v, int bf) {
    if (bf) ((bf16*)p)[i] = __float2bfloat16(v);
    else    ((float*)p)[i] = v;
}
__device__ __forceinline__ float lds_scalar(const void* p, int bf) {
    if (!bf) return *(const float*)p;
    float v = b2f(*(const bf16*)p);
    float a = fabsf(v);
    return (a >= 0.0009765625f && a <= 1024.0f) ? v : *(const float*)p;
}
__device__ __forceinline__ int get_flag(const float* ws) {
    return *(const int*)(ws + OFF_FLAG);
}
__device__ __forceinline__ void* e_base(void* d_out, int bf) {
    return bf ? (void*)((bf16*)d_out + NB) : (void*)((float*)d_out + NB);
}

// ---------------- kernels ----------------

// Detect element dtype of x (N(0,1) data).
__global__ void k_detect(const unsigned short* __restrict__ xu, float* __restrict__ ws) {
    __shared__ int cnt;
    if (threadIdx.x == 0) cnt = 0;
    __syncthreads();
    int c = 0;
    for (int i = threadIdx.x; i < 512; i += 256) {
        unsigned e = (xu[i] >> 7) & 0xFFu;
        if (e >= 110u && e <= 135u) c++;
    }
    atomicAdd(&cnt, c);
    __syncthreads();
    if (threadIdx.x == 0) *(int*)(ws + OFF_FLAG) = (cnt >= 460) ? 1 : 0;
}

// Pack all weights into bf16 MFMA-fragment order; zero BN accumulators + degrees.
// Fragment flat index t: i=t&7, l=(t>>3)&63, then (n,s) -> k = s*32+(l>>4)*8+i,
// c = n*16+(l&15).  (verified on-harness by round-2 k_edge1_mfma)
__global__ void k_init(float* __restrict__ ws, const void* __restrict__ W_e,
                       const void* __restrict__ W_m1, const void* __restrict__ W_m2) {
    int bf = get_flag(ws);
    size_t gid = (size_t)blockIdx.x * blockDim.x + threadIdx.x;
    size_t stride = (size_t)gridDim.x * blockDim.x;
    // WB: W_e rows 256..383  (K=128 -> s:4, N=128 -> n:8)
    short* WB = (short*)(ws + OFF_WB);
    for (size_t t = gid; t < 16384; t += stride) {
        int i = t & 7, l = (t >> 3) & 63, n = (t >> 9) & 7, s = t >> 12;
        int k = s * 32 + (l >> 4) * 8 + i;
        int c = n * 16 + (l & 15);
        WB[t] = f2bs(ldf(W_e, (size_t)(256 + k) * 128 + c, bf));
    }
    // WP: cols 0..127 = W_e rows 0..127 (xa), cols 128..255 = W_e rows 128..255 (xb)
    short* WP = (short*)(ws + OFF_WP);
    for (size_t t = gid; t < 32768; t += stride) {
        int i = t & 7, l = (t >> 3) & 63, n = (t >> 9) & 15, s = t >> 13;
        int k = s * 32 + (l >> 4) * 8 + i;
        int c = n * 16 + (l & 15);
        float v = (c < 128) ? ldf(W_e, (size_t)k * 128 + c, bf)
                            : ldf(W_e, (size_t)(128 + k) * 128 + (c - 128), bf);
        WP[t] = f2bs(v);
    }
    // WM1: [128 x 256]  (s:4, n:16)
    short* M1 = (short*)(ws + OFF_WM1P);
    for (size_t t = gid; t < 32768; t += stride) {
        int i = t & 7, l = (t >> 3) & 63, n = (t >> 9) & 15, s = t >> 13;
        int k = s * 32 + (l >> 4) * 8 + i;
        int c = n * 16 + (l & 15);
        M1[t] = f2bs(ldf(W_m1, (size_t)k * 256 + c, bf));
    }
    // WM2: [256 x 128]  (s:8, n:8)
    short* M2 = (short*)(ws + OFF_WM2P);
    for (size_t t = gid; t < 32768; t += stride) {
        int i = t & 7, l = (t >> 3) & 63, n = (t >> 9) & 7, s = t >> 12;
        int k = s * 32 + (l >> 4) * 8 + i;
        int c = n * 16 + (l & 15);
        M2[t] = f2bs(ldf(W_m2, (size_t)k * 128 + c, bf));
    }
    for (size_t i = gid; i < 512; i += stride) ws[OFF_BNS + i] = 0.0f;
    int* deg = (int*)(ws + OFF_DEG);
    for (size_t i = gid; i < N; i += stride) deg[i] = 0;
}

// Per 64 nodes (4 waves x 16 rows): [xa|xb] = x @ WP (+b_e on xa), bf16 -> XA|XB.
// Also row ||x|| from the A-fragment values.
__global__ __launch_bounds__(256) void k_node_pre_mfma(const void* __restrict__ x,
                                                       const void* __restrict__ b_e,
                                                       float* __restrict__ ws) {
    int bf = get_flag(ws);
    int l = threadIdx.x & 63, wv = threadIdx.x >> 6;
    int n0 = blockIdx.x * 64 + wv * 16;
    if (n0 >= N) return;
    int row = l & 15, grp = l >> 4;
    int ja = n0 + row;
    int jac = ja < N ? ja : N - 1;
    const short8v* WP = (const short8v*)(ws + OFF_WP);
    float4v acc[16];
    #pragma unroll
    for (int n = 0; n < 16; ++n) acc[n] = (float4v){0.f, 0.f, 0.f, 0.f};
    float sq = 0.f;
    #pragma unroll
    for (int s = 0; s < 4; ++s) {
        short8v af;
        if (bf) {
            af = ((const short8v*)x)[(size_t)jac * 16 + s * 4 + grp];
            #pragma unroll
            for (int i = 0; i < 8; ++i) { float v = bs2f(af[i]); sq = fmaf(v, v, sq); }
        } else {
            const float* er = (const float*)x + (size_t)jac * 128 + s * 32 + grp * 8;
            float4v lo = *(const float4v*)er;
            float4v hi = *(const float4v*)(er + 4);
            float xv[8] = {lo[0], lo[1], lo[2], lo[3], hi[0], hi[1], hi[2], hi[3]};
            #pragma unroll
            for (int i = 0; i < 8; ++i) { sq = fmaf(xv[i], xv[i], sq); af[i] = f2bs(xv[i]); }
        }
        #pragma unroll
        for (int n = 0; n < 16; ++n) {
            acc[n] = __builtin_amdgcn_mfma_f32_16x16x32_bf16(af, WP[(s * 16 + n) * 64 + l], acc[n], 0, 0, 0);
        }
    }
    sq += __shfl_xor(sq, 16, 64);
    sq += __shfl_xor(sq, 32, 64);
    if (grp == 0 && ja < N) ws[OFF_XN + ja] = sqrtf(sq);
    bf16* XA = (bf16*)(ws + OFF_A);
    #pragma unroll
    for (int reg = 0; reg < 4; ++reg) {
        int jd = n0 + grp * 4 + reg;
        if (jd >= N) continue;
        #pragma unroll
        for (int n = 0; n < 16; ++n) {
            int c = n * 16 + row;
            if (n < 8) {
                XA[(size_t)jd * 128 + c] = __float2bfloat16(acc[n][reg] + ldf(b_e, c, bf));
            } else {
                XA[NB + (size_t)jd * 128 + (c - 128)] = __float2bfloat16(acc[n][reg]);
            }
        }
    }
}

// Per-edge MLP via MFMA. Each wave: 16 edges x 128 out channels.
//   pre = XA[r] + XB[cd] + ea @ W3   (XA has b_e folded in)
//   e   = LN(relu(pre)) * g + b + ea
__global__ __launch_bounds__(256) void k_edge1_mfma(const void* __restrict__ ea,
                                                    const int* __restrict__ ei,
                                                    const void* __restrict__ g_e,
                                                    const void* __restrict__ be_e,
                                                    float* __restrict__ ws,
                                                    void* __restrict__ d_out) {
    int bf = get_flag(ws);
    void* eo = e_base(d_out, bf);
    int l = threadIdx.x & 63;
    int wv = threadIdx.x >> 6;
    int e0w = blockIdx.x * 64 + wv * 16;
    if (e0w >= E) return;

    if (l < 16) {
        int j = e0w + l;
        if (j < E) atomicAdd((int*)(ws + OFF_DEG) + ei[E + j], 1);
    }

    int row = l & 15, grp = l >> 4;
    int ja = e0w + row;
    int jac = ja < E ? ja : E - 1;
    const short8v* WB = (const short8v*)(ws + OFF_WB);
    float4v acc[8];
    #pragma unroll
    for (int n = 0; n < 8; ++n) acc[n] = (float4v){0.f, 0.f, 0.f, 0.f};

    #pragma unroll
    for (int s = 0; s < 4; ++s) {
        short8v af;
        if (bf) {
            af = ((const short8v*)ea)[(size_t)jac * 16 + s * 4 + grp];
        } else {
            const float* er = (const float*)ea + (size_t)jac * 128 + s * 32 + grp * 8;
            float4v lo = *(const float4v*)er;
            float4v hi = *(const float4v*)(er + 4);
            af[0] = f2bs(lo[0]); af[1] = f2bs(lo[1]); af[2] = f2bs(lo[2]); af[3] = f2bs(lo[3]);
            af[4] = f2bs(hi[0]); af[5] = f2bs(hi[1]); af[6] = f2bs(hi[2]); af[7] = f2bs(hi[3]);
        }
        #pragma unroll
        for (int n = 0; n < 8; ++n) {
            acc[n] = __builtin_amdgcn_mfma_f32_16x16x32_bf16(af, WB[(s * 8 + n) * 64 + l], acc[n], 0, 0, 0);
        }
    }

    int jr[4], rr[4], cc[4];
    #pragma unroll
    for (int reg = 0; reg < 4; ++reg) {
        int j = e0w + grp * 4 + reg;
        int jc = j < E ? j : E - 1;
        jr[reg] = j;
        rr[reg] = ei[jc];
        cc[reg] = ei[E + jc];
    }
    const bf16* XA = (const bf16*)(ws + OFF_A);
    float p[8][4];
    #pragma unroll
    for (int n = 0; n < 8; ++n) {
        int col = n * 16 + row;
        #pragma unroll
        for (int reg = 0; reg < 4; ++reg) {
            float v = acc[n][reg]
                    + b2f(XA[(size_t)rr[reg] * 128 + col])
                    + b2f(XA[NB + (size_t)cc[reg] * 128 + col]);
            p[n][reg] = fmaxf(v, 0.f);
        }
    }
    #pragma unroll
    for (int reg = 0; reg < 4; ++reg) {
        float s1 = 0.f;
        #pragma unroll
        for (int n = 0; n < 8; ++n) s1 += p[n][reg];
        #pragma unroll
        for (int off = 1; off < 16; off <<= 1) s1 += __shfl_xor(s1, off, 64);
        float mu = s1 * (1.f / 128.f);
        float s2 = 0.f;
        #pragma unroll
        for (int n = 0; n < 8; ++n) { float d = p[n][reg] - mu; s2 = fmaf(d, d, s2); }
        #pragma unroll
        for (int off = 1; off < 16; off <<= 1) s2 += __shfl_xor(s2, off, 64);
        float rstd = rsqrtf(s2 * (1.f / 128.f) + 1e-5f);
        if (jr[reg] < E) {
            size_t jb = (size_t)jr[reg] * 128;
            #pragma unroll
            for (int n = 0; n < 8; ++n) {
                int col = n * 16 + row;
                float ev = (p[n][reg] - mu) * rstd * ldf(g_e, col, bf)
                         + ldf(be_e, col, bf) + ldf(ea, jb + col, bf);
                stf(eo, jb + col, ev, bf);
            }
        }
    }
}

// Exclusive scan of degree counts -> CSR offsets + scatter cursors. 1 block.
__global__ __launch_bounds__(256) void k_scan(float* __restrict__ ws) {
    const int* deg = (const int*)(ws + OFF_DEG);
    int* offs = (int*)(ws + OFF_OFFS);
    int* cur  = (int*)(ws + OFF_CUR);
    __shared__ int sums[256];
    __shared__ int carry[257];
    int t = threadIdx.x;
    const int chunk = (N + 255) / 256;
    int lo = t * chunk, hi = lo + chunk < N ? lo + chunk : N;
    int s = 0;
    for (int i = lo; i < hi; ++i) s += deg[i];
    sums[t] = s;
    __syncthreads();
    if (t == 0) {
        int acc = 0;
        #pragma unroll 4
        for (int i = 0; i < 256; ++i) { carry[i] = acc; acc += sums[i]; }
        carry[256] = acc;
    }
    __syncthreads();
    int acc = carry[t];
    for (int i = lo; i < hi; ++i) { offs[i] = acc; cur[i] = acc; acc += deg[i]; }
    if (t == 0) offs[N] = carry[256];
}

// Scatter edge ids into CSR list by destination.
__global__ void k_scatter(const int* __restrict__ ei, float* __restrict__ ws) {
    int j = blockIdx.x * blockDim.x + threadIdx.x;
    if (j >= E) return;
    int cd = ei[E + j];
    int pos = atomicAdd((int*)(ws + OFF_CUR) + cd, 1);
    ((int*)(ws + OFF_LIST))[pos] = j;
}

// Per node: gather incident edges, softmax-aggregate in registers (fixed-shift
// exp; softmax is shift-invariant and 0 <= msg*t <~ 22). out = agg + x -> bf16.
__global__ __launch_bounds__(256) void k_agg(const void* __restrict__ x,
                                             const int* __restrict__ ei,
                                             const void* __restrict__ t_p,
                                             void* __restrict__ d_out,
                                             float* __restrict__ ws) {
    int bf = get_flag(ws);
    const void* e_in = e_base(d_out, bf);
    int n = blockIdx.x, tid = threadIdx.x;
    int c = tid & 127, half = tid >> 7;
    const int* offs = (const int*)(ws + OFF_OFFS);
    const int* list = (const int*)(ws + OFF_LIST);
    int s0 = offs[n], s1 = offs[n + 1];
    float t = lds_scalar(t_p, bf);
    float den = 0.f, num = 0.f;
    for (int i = s0 + half; i < s1; i += 2) {
        int j = list[i];
        int r = ei[j];
        float ev = ldf(e_in, (size_t)j * 128 + c, bf);
        float msg = fmaxf(ldf(x, (size_t)r * 128 + c, bf) + ev, 0.f) + 1e-7f;
        float ex = expf(msg * t - 15.0f);
        den += ex;
        num = fmaf(msg, ex, num);
    }
    __shared__ float dsh[256];
    __shared__ float nsh[256];
    dsh[tid] = den;
    nsh[tid] = num;
    __syncthreads();
    if (tid < 128) {
        float dn = dsh[tid] + dsh[tid + 128];
        float nm = nsh[tid] + nsh[tid + 128];
        float ag = dn > 0.f ? nm / dn : 0.f;
        float out = ag + ldf(x, (size_t)n * 128 + tid, bf);
        ((bf16*)(ws + OFF_OUT))[(size_t)n * 128 + tid] = __float2bfloat16(out);
    }
}

// H1 = out @ W_m1 + b_m1  (bf16, N x 256), 64 nodes per block.
__global__ __launch_bounds__(256) void k_h1_mfma(const void* __restrict__ b_m1,
                                                 float* __restrict__ ws) {
    int bf = get_flag(ws);
    int l = threadIdx.x & 63, wv = threadIdx.x >> 6;
    int n0 = blockIdx.x * 64 + wv * 16;
    if (n0 >= N) return;
    int row = l & 15, grp = l >> 4;
    int ja = n0 + row;
    int jac = ja < N ? ja : N - 1;
    const short8v* OUT = (const short8v*)(ws + OFF_OUT);
    const short8v* M1 = (const short8v*)(ws + OFF_WM1P);
    float4v acc[16];
    #pragma unroll
    for (int n = 0; n < 16; ++n) acc[n] = (float4v){0.f, 0.f, 0.f, 0.f};
    #pragma unroll
    for (int s = 0; s < 4; ++s) {
        short8v af = OUT[(size_t)jac * 16 + s * 4 + grp];
        #pragma unroll
        for (int n = 0; n < 16; ++n) {
            acc[n] = __builtin_amdgcn_mfma_f32_16x16x32_bf16(af, M1[(s * 16 + n) * 64 + l], acc[n], 0, 0, 0);
        }
    }
    bf16* H1 = (bf16*)(ws + OFF_A);
    #pragma unroll
    for (int reg = 0; reg < 4; ++reg) {
        int jd = n0 + grp * 4 + reg;
        if (jd >= N) continue;
        #pragma unroll
        for (int n = 0; n < 16; ++n) {
            int col = n * 16 + row;
            H1[(size_t)jd * 256 + col] = __float2bfloat16(acc[n][reg] + ldf(b_m1, col, bf));
        }
    }
}

// BatchNorm statistics: column sums / sumsq of H1 over N rows.
__global__ __launch_bounds__(256) void k_bnstats(float* __restrict__ ws) {
    int t = threadIdx.x;
    const bf16* H1 = (const bf16*)(ws + OFF_A);
    float s = 0.f, q = 0.f;
    for (int r = blockIdx.x; r < N; r += gridDim.x) {
        float v = b2f(H1[(size_t)r * 256 + t]);
        s += v;
        q = fmaf(v, v, q);
    }
    atomicAdd(&ws[OFF_BNS + t], s);
    atomicAdd(&ws[OFF_BNQ + t], q);
}

// Per 64 nodes: hbn = relu(BN(H1)) built in-register as A-fragment;
// h = hbn @ W_m2 + b_m2; MessageNorm; residual + LayerNorm -> x_out.
__global__ __launch_bounds__(256) void k_node_post_mfma(const void* __restrict__ x,
                                                        const void* __restrict__ g_bn,
                                                        const void* __restrict__ b_bn,
                                                        const void* __restrict__ b_m2,
                                                        const void* __restrict__ scale_p,
                                                        const void* __restrict__ g_n,
                                                        const void* __restrict__ b_n,
                                                        float* __restrict__ ws,
                                                        void* __restrict__ x_out) {
    int bf = get_flag(ws);
    __shared__ float sA[256];   // per-col BN scale = rstd*g
    __shared__ float sB[256];   // per-col BN shift = b - mu*rstd*g
    {
        int t = threadIdx.x;
        const float inv_n = 1.f / (float)N;
        float mu = ws[OFF_BNS + t] * inv_n;
        float var = ws[OFF_BNQ + t] * inv_n - mu * mu;
        float rs = rsqrtf(fmaxf(var, 0.f) + 1e-5f) * ldf(g_bn, t, bf);
        sA[t] = rs;
        sB[t] = ldf(b_bn, t, bf) - mu * rs;
    }
    __syncthreads();
    int l = threadIdx.x & 63, wv = threadIdx.x >> 6;
    int n0 = blockIdx.x * 64 + wv * 16;
    if (n0 >= N) return;
    int row = l & 15, grp = l >> 4;
    int ja = n0 + row;
    int jac = ja < N ? ja : N - 1;
    const short8v* H1 = (const short8v*)(ws + OFF_A);
    const short8v* M2 = (const short8v*)(ws + OFF_WM2P);
    float4v acc[8];
    #pragma unroll
    for (int n = 0; n < 8; ++n) acc[n] = (float4v){0.f, 0.f, 0.f, 0.f};
    #pragma unroll
    for (int s = 0; s < 8; ++s) {
        short8v hv = H1[(size_t)jac * 32 + s * 4 + grp];
        int kb = s * 32 + grp * 8;
        short8v af;
        #pragma unroll
        for (int i = 0; i < 8; ++i) {
            float v = fmaf(bs2f(hv[i]), sA[kb + i], sB[kb + i]);
            af[i] = f2bs(fmaxf(v, 0.f));
        }
        #pragma unroll
        for (int n = 0; n < 8; ++n) {
            acc[n] = __builtin_amdgcn_mfma_f32_16x16x32_bf16(af, M2[(s * 8 + n) * 64 + l], acc[n], 0, 0, 0);
        }
    }
    float scl = lds_scalar(scale_p, bf);
    #pragma unroll
    for (int reg = 0; reg < 4; ++reg) {
        int jd = n0 + grp * 4 + reg;
        int jdc = jd < N ? jd : N - 1;
        float h[8];
        float ss = 0.f;
        #pragma unroll
        for (int n = 0; n < 8; ++n) {
            h[n] = acc[n][reg] + ldf(b_m2, n * 16 + row, bf);
            ss = fmaf(h[n], h[n], ss);
        }
        #pragma unroll
        for (int off = 1; off < 16; off <<= 1) ss += __shfl_xor(ss, off, 64);
        float hs = ws[OFF_XN + jdc] * scl / fmaxf(sqrtf(ss), 1e-12f);
        float y[8];
        float s1 = 0.f;
        #pragma unroll
        for (int n = 0; n < 8; ++n) {
            y[n] = ldf(x, (size_t)jdc * 128 + n * 16 + row, bf) + h[n] * hs;
            s1 += y[n];
        }
        #pragma unroll
        for (int off = 1; off < 16; off <<= 1) s1 += __shfl_xor(s1, off, 64);
        float mu = s1 * (1.f / 128.f);
        float s2 = 0.f;
        #pragma unroll
        for (int n = 0; n < 8; ++n) { float d = y[n] - mu; s2 = fmaf(d, d, s2); }
        #pragma unroll
        for (int off = 1; off < 16; off <<= 1) s2 += __shfl_xor(s2, off, 64);
        float rstd = rsqrtf(s2 * (1.f / 128.f) + 1e-5f);
        if (jd < N) {
            #pragma unroll
            for (int n = 0; n < 8; ++n) {
                int col = n * 16 + row;
                float o = (y[n] - mu) * rstd * ldf(g_n, col, bf) + ldf(b_n, col, bf);
                stf(x_out, (size_t)jd * 128 + col, o, bf);
            }
        }
    }
}

// ---------------- launcher ----------------

extern "C" void kernel_launch(void* const* d_in, const int* in_sizes, int n_in,
                              void* d_out, int out_size, void* d_ws, size_t ws_size,
                              hipStream_t stream) {
    const void* x    = d_in[0];
    const void* ea   = d_in[1];
    const int*  ei   = (const int*)d_in[2];
    const void* W_e  = d_in[3];
    const void* b_e  = d_in[4];
    const void* g_e  = d_in[5];
    const void* be_e = d_in[6];
    const void* t_p  = d_in[7];
    const void* W_m1 = d_in[8];
    const void* b_m1 = d_in[9];
    const void* g_bn = d_in[10];
    const void* b_bn = d_in[11];
    const void* W_m2 = d_in[12];
    const void* b_m2 = d_in[13];
    const void* scl  = d_in[14];
    const void* g_n  = d_in[15];
    const void* b_n  = d_in[16];

    float* ws = (float*)d_ws;

    k_detect<<<1, 256, 0, stream>>>((const unsigned short*)x, ws);
    k_init<<<512, 256, 0, stream>>>(ws, W_e, W_m1, W_m2);
    k_node_pre_mfma<<<NBLK, 256, 0, stream>>>(x, b_e, ws);
    k_edge1_mfma<<<(E + 63) / 64, 256, 0, stream>>>(ea, ei, g_e, be_e, ws, d_out);
    k_scan<<<1, 256, 0, stream>>>(ws);
    k_scatter<<<(E + 255) / 256, 256, 0, stream>>>(ei, ws);
    k_agg<<<N, 256, 0, stream>>>(x, ei, t_p, d_out, ws);
    k_h1_mfma<<<NBLK, 256, 0, stream>>>(b_m1, ws);
    k_bnstats<<<256, 256, 0, stream>>>(ws);
    k_node_post_mfma<<<NBLK, 256, 0, stream>>>(x, g_bn, b_bn, b_m2, scl, g_n, b_n, ws, d_out);
}

// Round 5
// 604.546 us; speedup vs baseline: 2.1500x; 1.0290x over previous
//
#include <hip/hip_runtime.h>
#include <hip/hip_bf16.h>

typedef __hip_bfloat16 bf16;
typedef __attribute__((ext_vector_type(8))) short short8v;   // 8 bf16 (4 VGPRs)
typedef __attribute__((ext_vector_type(4))) short short4v;   // 4 bf16 (8B)
typedef __attribute__((ext_vector_type(4))) float float4v;   // MFMA acc / 16B vec

constexpr int N = 25000;
constexpr int E = 250000;
constexpr size_t NB = (size_t)N * 128;            // 3,200,000
constexpr int NBLK = (N + 63) / 64;               // 391 node-tiles of 64

constexpr size_t al256(size_t x) { return (x + 255) / 256 * 256; }

// Workspace layout (float element offsets).
constexpr size_t OFF_BNS  = 0;                    // 256 f32 BN col sums
constexpr size_t OFF_BNQ  = OFF_BNS + 256;        // 256 f32 BN col sumsq
constexpr size_t OFF_FLAG = OFF_BNQ + 256;        // dtype flag (int in slot 0)
constexpr size_t OFF_XN   = OFF_FLAG + 256;       // N f32 ||x|| per row
constexpr size_t OFF_WB   = al256(OFF_XN + N);    // W3   bf16 frag-packed 16384 (8192 f32)
constexpr size_t OFF_WP   = OFF_WB + 8192;        // W1|W2 bf16 frag-packed 32768 (16384 f32)
constexpr size_t OFF_WM1P = OFF_WP + 16384;       // W_m1 bf16 frag-packed 32768
constexpr size_t OFF_WM2P = OFF_WM1P + 16384;     // W_m2 bf16 frag-packed 32768
constexpr size_t OFF_DEG  = al256(OFF_WM2P + 16384); // int[N] in-degree
constexpr size_t OFF_OFFS = al256(OFF_DEG + N);   // int[N+1] CSR offsets
constexpr size_t OFF_CUR  = al256(OFF_OFFS + N + 1); // int[N] cursors
constexpr size_t OFF_LIST = al256(OFF_CUR + N);   // int[E] edge ids by dest (fallback only)
constexpr size_t OFF_OUT  = al256(OFF_LIST + E);  // out = agg+x, N*128 bf16 (NB/2 f32)
constexpr size_t OFF_A    = al256(OFF_OUT + NB / 2);
// Region A: NB f32 slots (= 2*NB bf16), reused twice:
//   phase 1: XA [0,NB) bf16 | XB [NB,2NB) bf16
//   phase 2: H1 [0,2NB) bf16 (N x 256) overlays XA|XB
constexpr size_t WS_FLOATS = OFF_A + NB;          // ~21 MB (fallback footprint)
// Big path: MSG = E x 128 bf16 in CSR order (64 MB), appended past region A.
constexpr size_t OFF_MSG  = al256(OFF_A + NB);    // E*64 f32 slots
constexpr size_t WS_FLOATS_BIG = OFF_MSG + (size_t)E * 64;   // ~85 MB

// ---------------- dtype-agnostic access ----------------

__device__ __forceinline__ float b2f(bf16 v) { return __bfloat162float(v); }
__device__ __forceinline__ short f2bs(float f) {
    bf16 h = __float2bfloat16(f);
    return *reinterpret_cast<short*>(&h);
}
__device__ __forceinline__ float bs2f(short s) {
    bf16 h;
    *reinterpret_cast<short*>(&h) = s;
    return b2f(h);
}

__device__ __forceinline__ float ldf(const void* p, size_t i, int bf) {
    return bf ? b2f(((const bf16*)p)[i]) : ((const float*)p)[i];
}
__device__ __forceinline__ void stf(void* p, size_t i, float v, int bf) {
    if (bf) ((bf16*)p)[i] = __float2bfloat16(v);
    else    ((float*)p)[i] = v;
}
__device__ __forceinline__ float4v load4(const void* p, size_t i, int bf) {
    if (bf) {
        short4v s = *(const short4v*)((const bf16*)p + i);
        return (float4v){bs2f(s[0]), bs2f(s[1]), bs2f(s[2]), bs2f(s[3])};
    }
    return *(const float4v*)((const float*)p + i);
}
__device__ __forceinline__ void store4(void* p, size_t i, float4v v, int bf) {
    if (bf) {
        short4v s = {f2bs(v[0]), f2bs(v[1]), f2bs(v[2]), f2bs(v[3])};
        *(short4v*)((bf16*)p + i) = s;
    } else {
        *(float4v*)((float*)p + i) = v;
    }
}
__device__ __forceinline__ float lds_scalar(const void* p, int bf) {
    if (!bf) return *(const float*)p;
    float v = b2f(*(const bf16*)p);
    float a = fabsf(v);
    return (a >= 0.0009765625f && a <= 1024.0f) ? v : *(const float*)p;
}
__device__ __forceinline__ int get_flag(const float* ws) {
    return *(const int*)(ws + OFF_FLAG);
}
__device__ __forceinline__ void* e_base(void* d_out, int bf) {
    return bf ? (void*)((bf16*)d_out + NB) : (void*)((float*)d_out + NB);
}

// ---------------- kernels ----------------

// Detect element dtype of x (N(0,1) data).
__global__ void k_detect(const unsigned short* __restrict__ xu, float* __restrict__ ws) {
    __shared__ int cnt;
    if (threadIdx.x == 0) cnt = 0;
    __syncthreads();
    int c = 0;
    for (int i = threadIdx.x; i < 512; i += 256) {
        unsigned e = (xu[i] >> 7) & 0xFFu;
        if (e >= 110u && e <= 135u) c++;
    }
    atomicAdd(&cnt, c);
    __syncthreads();
    if (threadIdx.x == 0) *(int*)(ws + OFF_FLAG) = (cnt >= 460) ? 1 : 0;
}

// Pack all weights into bf16 MFMA-fragment order; zero BN accumulators + degrees.
// Fragment flat index t: i=t&7, l=(t>>3)&63, then (n,s) -> k = s*32+(l>>4)*8+i,
// c = n*16+(l&15).  (verified on-harness by round-2 k_edge1_mfma)
__global__ void k_init(float* __restrict__ ws, const void* __restrict__ W_e,
                       const void* __restrict__ W_m1, const void* __restrict__ W_m2) {
    int bf = get_flag(ws);
    size_t gid = (size_t)blockIdx.x * blockDim.x + threadIdx.x;
    size_t stride = (size_t)gridDim.x * blockDim.x;
    // WB: W_e rows 256..383  (K=128 -> s:4, N=128 -> n:8)
    short* WB = (short*)(ws + OFF_WB);
    for (size_t t = gid; t < 16384; t += stride) {
        int i = t & 7, l = (t >> 3) & 63, n = (t >> 9) & 7, s = t >> 12;
        int k = s * 32 + (l >> 4) * 8 + i;
        int c = n * 16 + (l & 15);
        WB[t] = f2bs(ldf(W_e, (size_t)(256 + k) * 128 + c, bf));
    }
    // WP: cols 0..127 = W_e rows 0..127 (xa), cols 128..255 = W_e rows 128..255 (xb)
    short* WP = (short*)(ws + OFF_WP);
    for (size_t t = gid; t < 32768; t += stride) {
        int i = t & 7, l = (t >> 3) & 63, n = (t >> 9) & 15, s = t >> 13;
        int k = s * 32 + (l >> 4) * 8 + i;
        int c = n * 16 + (l & 15);
        float v = (c < 128) ? ldf(W_e, (size_t)k * 128 + c, bf)
                            : ldf(W_e, (size_t)(128 + k) * 128 + (c - 128), bf);
        WP[t] = f2bs(v);
    }
    // WM1: [128 x 256]  (s:4, n:16)
    short* M1 = (short*)(ws + OFF_WM1P);
    for (size_t t = gid; t < 32768; t += stride) {
        int i = t & 7, l = (t >> 3) & 63, n = (t >> 9) & 15, s = t >> 13;
        int k = s * 32 + (l >> 4) * 8 + i;
        int c = n * 16 + (l & 15);
        M1[t] = f2bs(ldf(W_m1, (size_t)k * 256 + c, bf));
    }
    // WM2: [256 x 128]  (s:8, n:8)
    short* M2 = (short*)(ws + OFF_WM2P);
    for (size_t t = gid; t < 32768; t += stride) {
        int i = t & 7, l = (t >> 3) & 63, n = (t >> 9) & 7, s = t >> 12;
        int k = s * 32 + (l >> 4) * 8 + i;
        int c = n * 16 + (l & 15);
        M2[t] = f2bs(ldf(W_m2, (size_t)k * 128 + c, bf));
    }
    for (size_t i = gid; i < 512; i += stride) ws[OFF_BNS + i] = 0.0f;
    int* deg = (int*)(ws + OFF_DEG);
    for (size_t i = gid; i < N; i += stride) deg[i] = 0;
}

// In-degree counts (runs before k_scan / k_edge1).
__global__ void k_count(const int* __restrict__ ei, float* __restrict__ ws) {
    int j = blockIdx.x * blockDim.x + threadIdx.x;
    if (j < E) atomicAdd((int*)(ws + OFF_DEG) + ei[E + j], 1);
}

// Per 64 nodes (4 waves x 16 rows): [xa|xb] = x @ WP (+b_e on xa), bf16 -> XA|XB.
// Also row ||x|| from the A-fragment values.
__global__ __launch_bounds__(256) void k_node_pre_mfma(const void* __restrict__ x,
                                                       const void* __restrict__ b_e,
                                                       float* __restrict__ ws) {
    int bf = get_flag(ws);
    int l = threadIdx.x & 63, wv = threadIdx.x >> 6;
    int n0 = blockIdx.x * 64 + wv * 16;
    if (n0 >= N) return;
    int row = l & 15, grp = l >> 4;
    int ja = n0 + row;
    int jac = ja < N ? ja : N - 1;
    const short8v* WP = (const short8v*)(ws + OFF_WP);
    float4v acc[16];
    #pragma unroll
    for (int n = 0; n < 16; ++n) acc[n] = (float4v){0.f, 0.f, 0.f, 0.f};
    float sq = 0.f;
    #pragma unroll
    for (int s = 0; s < 4; ++s) {
        short8v af;
        if (bf) {
            af = ((const short8v*)x)[(size_t)jac * 16 + s * 4 + grp];
            #pragma unroll
            for (int i = 0; i < 8; ++i) { float v = bs2f(af[i]); sq = fmaf(v, v, sq); }
        } else {
            const float* er = (const float*)x + (size_t)jac * 128 + s * 32 + grp * 8;
            float4v lo = *(const float4v*)er;
            float4v hi = *(const float4v*)(er + 4);
            float xv[8] = {lo[0], lo[1], lo[2], lo[3], hi[0], hi[1], hi[2], hi[3]};
            #pragma unroll
            for (int i = 0; i < 8; ++i) { sq = fmaf(xv[i], xv[i], sq); af[i] = f2bs(xv[i]); }
        }
        #pragma unroll
        for (int n = 0; n < 16; ++n) {
            acc[n] = __builtin_amdgcn_mfma_f32_16x16x32_bf16(af, WP[(s * 16 + n) * 64 + l], acc[n], 0, 0, 0);
        }
    }
    sq += __shfl_xor(sq, 16, 64);
    sq += __shfl_xor(sq, 32, 64);
    if (grp == 0 && ja < N) ws[OFF_XN + ja] = sqrtf(sq);
    bf16* XA = (bf16*)(ws + OFF_A);
    #pragma unroll
    for (int reg = 0; reg < 4; ++reg) {
        int jd = n0 + grp * 4 + reg;
        if (jd >= N) continue;
        #pragma unroll
        for (int n = 0; n < 16; ++n) {
            int c = n * 16 + row;
            if (n < 8) {
                XA[(size_t)jd * 128 + c] = __float2bfloat16(acc[n][reg] + ldf(b_e, c, bf));
            } else {
                XA[NB + (size_t)jd * 128 + (c - 128)] = __float2bfloat16(acc[n][reg]);
            }
        }
    }
}

// Per-edge MLP via MFMA, operand-SWAPPED so D[ch][edge]: lane holds one edge
// (col = l&15) x 32 channels in 4-contiguous chunks (ch = m*16 + grp*4 + w).
//   pre = XA[r] + XB[cd] + ea @ W3   (XA has b_e folded in)
//   e   = LN(relu(pre)) * g + b + ea
// WM: also write msg = relu(x[r]+e)+eps as bf16 into MSG at CSR position.
template<int WM>
__global__ __launch_bounds__(256) void k_edge1_mfma(const void* __restrict__ ea,
                                                    const int* __restrict__ ei,
                                                    const void* __restrict__ g_e,
                                                    const void* __restrict__ be_e,
                                                    const void* __restrict__ x,
                                                    float* __restrict__ ws,
                                                    void* __restrict__ d_out) {
    int bf = get_flag(ws);
    void* eo = e_base(d_out, bf);
    int l = threadIdx.x & 63;
    int wv = threadIdx.x >> 6;
    int e0w = blockIdx.x * 64 + wv * 16;
    int eq = l & 15, grp = l >> 4;

    // CSR position claim: one lane per edge, then broadcast.
    int posv = 0;
    if (WM && l < 16) {
        int jj = e0w + l;
        if (jj < E) posv = atomicAdd((int*)(ws + OFF_CUR) + ei[E + jj], 1);
    }
    int pos = WM ? __shfl(posv, eq, 64) : 0;

    // ---- GEMM: acc[m] = W3_frag(A) x ea_frag(B) -> D[ch][edge] ----
    int ja = e0w + eq;
    int jac = ja < E ? ja : E - 1;
    const short8v* WB = (const short8v*)(ws + OFF_WB);
    float4v acc[8];
    #pragma unroll
    for (int m = 0; m < 8; ++m) acc[m] = (float4v){0.f, 0.f, 0.f, 0.f};

    #pragma unroll
    for (int s = 0; s < 4; ++s) {
        short8v bfr;   // B-fragment: ea[e0w+eq][s*32 + grp*8 + i]
        if (bf) {
            bfr = ((const short8v*)ea)[(size_t)jac * 16 + s * 4 + grp];
        } else {
            const float* er = (const float*)ea + (size_t)jac * 128 + s * 32 + grp * 8;
            float4v lo = *(const float4v*)er;
            float4v hi = *(const float4v*)(er + 4);
            bfr[0] = f2bs(lo[0]); bfr[1] = f2bs(lo[1]); bfr[2] = f2bs(lo[2]); bfr[3] = f2bs(lo[3]);
            bfr[4] = f2bs(hi[0]); bfr[5] = f2bs(hi[1]); bfr[6] = f2bs(hi[2]); bfr[7] = f2bs(hi[3]);
        }
        #pragma unroll
        for (int m = 0; m < 8; ++m) {
            acc[m] = __builtin_amdgcn_mfma_f32_16x16x32_bf16(WB[(s * 8 + m) * 64 + l], bfr, acc[m], 0, 0, 0);
        }
    }

    // ---- epilogue: this lane owns edge (e0w+eq), channels m*16+grp*4+w ----
    int j = e0w + eq;
    bool valid = j < E;
    int jc = valid ? j : E - 1;
    int r = ei[jc], cd = ei[E + jc];
    const bf16* XAp = (const bf16*)(ws + OFF_A);

    float p[8][4];
    float s1 = 0.f, s2 = 0.f;
    #pragma unroll
    for (int m = 0; m < 8; ++m) {
        int ch = m * 16 + grp * 4;
        short4v xa = *(const short4v*)(XAp + (size_t)r * 128 + ch);
        short4v xb = *(const short4v*)(XAp + NB + (size_t)cd * 128 + ch);
        #pragma unroll
        for (int w = 0; w < 4; ++w) {
            float v = acc[m][w] + bs2f(xa[w]) + bs2f(xb[w]);
            v = fmaxf(v, 0.f);
            p[m][w] = v;
            s1 += v;
            s2 = fmaf(v, v, s2);
        }
    }
    s1 += __shfl_xor(s1, 16, 64);
    s1 += __shfl_xor(s1, 32, 64);
    s2 += __shfl_xor(s2, 16, 64);
    s2 += __shfl_xor(s2, 32, 64);
    float mu = s1 * (1.f / 128.f);
    float var = s2 * (1.f / 128.f) - mu * mu;
    float rstd = rsqrtf(fmaxf(var, 0.f) + 1e-5f);

    bf16* MSG = (bf16*)(ws + OFF_MSG);
    #pragma unroll
    for (int m = 0; m < 8; ++m) {
        int ch = m * 16 + grp * 4;
        float4v gg = load4(g_e, ch, bf);
        float4v bb = load4(be_e, ch, bf);
        float4v eav = load4(ea, (size_t)jc * 128 + ch, bf);
        float4v ev;
        #pragma unroll
        for (int w = 0; w < 4; ++w)
            ev[w] = (p[m][w] - mu) * rstd * gg[w] + bb[w] + eav[w];
        if (valid) store4(eo, (size_t)j * 128 + ch, ev, bf);
        if (WM) {
            float4v xv = load4(x, (size_t)r * 128 + ch, bf);
            short4v ms;
            #pragma unroll
            for (int w = 0; w < 4; ++w)
                ms[w] = f2bs(fmaxf(xv[w] + ev[w], 0.f) + 1e-7f);
            if (valid) *(short4v*)(MSG + (size_t)pos * 128 + ch) = ms;
        }
    }
}

// Exclusive scan of degree counts -> CSR offsets + scatter cursors. 1 block.
__global__ __launch_bounds__(256) void k_scan(float* __restrict__ ws) {
    const int* deg = (const int*)(ws + OFF_DEG);
    int* offs = (int*)(ws + OFF_OFFS);
    int* cur  = (int*)(ws + OFF_CUR);
    __shared__ int sums[256];
    __shared__ int carry[257];
    int t = threadIdx.x;
    const int chunk = (N + 255) / 256;
    int lo = t * chunk, hi = lo + chunk < N ? lo + chunk : N;
    int s = 0;
    for (int i = lo; i < hi; ++i) s += deg[i];
    sums[t] = s;
    __syncthreads();
    if (t == 0) {
        int acc = 0;
        #pragma unroll 4
        for (int i = 0; i < 256; ++i) { carry[i] = acc; acc += sums[i]; }
        carry[256] = acc;
    }
    __syncthreads();
    int acc = carry[t];
    for (int i = lo; i < hi; ++i) { offs[i] = acc; cur[i] = acc; acc += deg[i]; }
    if (t == 0) offs[N] = carry[256];
}

// Scatter edge ids into CSR list by destination (fallback path only).
__global__ void k_scatter(const int* __restrict__ ei, float* __restrict__ ws) {
    int j = blockIdx.x * blockDim.x + threadIdx.x;
    if (j >= E) return;
    int cd = ei[E + j];
    int pos = atomicAdd((int*)(ws + OFF_CUR) + cd, 1);
    ((int*)(ws + OFF_LIST))[pos] = j;
}

// Big path: stream CSR-ordered MSG rows; softmax-aggregate (fixed-shift exp,
// shift-invariant; msg already includes +eps). out = agg + x -> OUT bf16.
__global__ __launch_bounds__(256) void k_agg_stream(const void* __restrict__ x,
                                                    const void* __restrict__ t_p,
                                                    float* __restrict__ ws) {
    int bf = get_flag(ws);
    int n = blockIdx.x, tid = threadIdx.x;
    int c = tid & 127, half = tid >> 7;
    const int* offs = (const int*)(ws + OFF_OFFS);
    int s0 = offs[n], s1v = offs[n + 1];
    float t = lds_scalar(t_p, bf);
    const bf16* MSG = (const bf16*)(ws + OFF_MSG);
    float den = 0.f, num = 0.f;
    for (int i = s0 + half; i < s1v; i += 2) {
        float m = b2f(MSG[(size_t)i * 128 + c]);
        float ex = expf(m * t - 15.0f);
        den += ex;
        num = fmaf(m, ex, num);
    }
    __shared__ float dsh[256];
    __shared__ float nsh[256];
    dsh[tid] = den;
    nsh[tid] = num;
    __syncthreads();
    if (tid < 128) {
        float dn = dsh[tid] + dsh[tid + 128];
        float nm = nsh[tid] + nsh[tid + 128];
        float ag = dn > 0.f ? nm / dn : 0.f;
        float out = ag + ldf(x, (size_t)n * 128 + tid, bf);
        ((bf16*)(ws + OFF_OUT))[(size_t)n * 128 + tid] = __float2bfloat16(out);
    }
}

// Fallback: gather incident edges via LIST, recompute msg from f32 e and x.
__global__ __launch_bounds__(256) void k_agg_gather(const void* __restrict__ x,
                                                    const int* __restrict__ ei,
                                                    const void* __restrict__ t_p,
                                                    void* __restrict__ d_out,
                                                    float* __restrict__ ws) {
    int bf = get_flag(ws);
    const void* e_in = e_base(d_out, bf);
    int n = blockIdx.x, tid = threadIdx.x;
    int c = tid & 127, half = tid >> 7;
    const int* offs = (const int*)(ws + OFF_OFFS);
    const int* list = (const int*)(ws + OFF_LIST);
    int s0 = offs[n], s1v = offs[n + 1];
    float t = lds_scalar(t_p, bf);
    float den = 0.f, num = 0.f;
    for (int i = s0 + half; i < s1v; i += 2) {
        int j = list[i];
        int r = ei[j];
        float ev = ldf(e_in, (size_t)j * 128 + c, bf);
        float msg = fmaxf(ldf(x, (size_t)r * 128 + c, bf) + ev, 0.f) + 1e-7f;
        float ex = expf(msg * t - 15.0f);
        den += ex;
        num = fmaf(msg, ex, num);
    }
    __shared__ float dsh[256];
    __shared__ float nsh[256];
    dsh[tid] = den;
    nsh[tid] = num;
    __syncthreads();
    if (tid < 128) {
        float dn = dsh[tid] + dsh[tid + 128];
        float nm = nsh[tid] + nsh[tid + 128];
        float ag = dn > 0.f ? nm / dn : 0.f;
        float out = ag + ldf(x, (size_t)n * 128 + tid, bf);
        ((bf16*)(ws + OFF_OUT))[(size_t)n * 128 + tid] = __float2bfloat16(out);
    }
}

// H1 = out @ W_m1 + b_m1  (bf16, N x 256), 64 nodes per block.
__global__ __launch_bounds__(256) void k_h1_mfma(const void* __restrict__ b_m1,
                                                 float* __restrict__ ws) {
    int bf = get_flag(ws);
    int l = threadIdx.x & 63, wv = threadIdx.x >> 6;
    int n0 = blockIdx.x * 64 + wv * 16;
    if (n0 >= N) return;
    int row = l & 15, grp = l >> 4;
    int ja = n0 + row;
    int jac = ja < N ? ja : N - 1;
    const short8v* OUT = (const short8v*)(ws + OFF_OUT);
    const short8v* M1 = (const short8v*)(ws + OFF_WM1P);
    float4v acc[16];
    #pragma unroll
    for (int n = 0; n < 16; ++n) acc[n] = (float4v){0.f, 0.f, 0.f, 0.f};
    #pragma unroll
    for (int s = 0; s < 4; ++s) {
        short8v af = OUT[(size_t)jac * 16 + s * 4 + grp];
        #pragma unroll
        for (int n = 0; n < 16; ++n) {
            acc[n] = __builtin_amdgcn_mfma_f32_16x16x32_bf16(af, M1[(s * 16 + n) * 64 + l], acc[n], 0, 0, 0);
        }
    }
    bf16* H1 = (bf16*)(ws + OFF_A);
    #pragma unroll
    for (int reg = 0; reg < 4; ++reg) {
        int jd = n0 + grp * 4 + reg;
        if (jd >= N) continue;
        #pragma unroll
        for (int n = 0; n < 16; ++n) {
            int col = n * 16 + row;
            H1[(size_t)jd * 256 + col] = __float2bfloat16(acc[n][reg] + ldf(b_m1, col, bf));
        }
    }
}

// BatchNorm statistics: column sums / sumsq of H1 over N rows.
__global__ __launch_bounds__(256) void k_bnstats(float* __restrict__ ws) {
    int t = threadIdx.x;
    const bf16* H1 = (const bf16*)(ws + OFF_A);
    float s = 0.f, q = 0.f;
    for (int r = blockIdx.x; r < N; r += gridDim.x) {
        float v = b2f(H1[(size_t)r * 256 + t]);
        s += v;
        q = fmaf(v, v, q);
    }
    atomicAdd(&ws[OFF_BNS + t], s);
    atomicAdd(&ws[OFF_BNQ + t], q);
}

// Per 64 nodes: hbn = relu(BN(H1)) built in-register as A-fragment;
// h = hbn @ W_m2 + b_m2; MessageNorm; residual + LayerNorm -> x_out.
__global__ __launch_bounds__(256) void k_node_post_mfma(const void* __restrict__ x,
                                                        const void* __restrict__ g_bn,
                                                        const void* __restrict__ b_bn,
                                                        const void* __restrict__ b_m2,
                                                        const void* __restrict__ scale_p,
                                                        const void* __restrict__ g_n,
                                                        const void* __restrict__ b_n,
                                                        float* __restrict__ ws,
                                                        void* __restrict__ x_out) {
    int bf = get_flag(ws);
    __shared__ float sA[256];   // per-col BN scale = rstd*g
    __shared__ float sB[256];   // per-col BN shift = b - mu*rstd*g
    {
        int t = threadIdx.x;
        const float inv_n = 1.f / (float)N;
        float mu = ws[OFF_BNS + t] * inv_n;
        float var = ws[OFF_BNQ + t] * inv_n - mu * mu;
        float rs = rsqrtf(fmaxf(var, 0.f) + 1e-5f) * ldf(g_bn, t, bf);
        sA[t] = rs;
        sB[t] = ldf(b_bn, t, bf) - mu * rs;
    }
    __syncthreads();
    int l = threadIdx.x & 63, wv = threadIdx.x >> 6;
    int n0 = blockIdx.x * 64 + wv * 16;
    if (n0 >= N) return;
    int row = l & 15, grp = l >> 4;
    int ja = n0 + row;
    int jac = ja < N ? ja : N - 1;
    const short8v* H1 = (const short8v*)(ws + OFF_A);
    const short8v* M2 = (const short8v*)(ws + OFF_WM2P);
    float4v acc[8];
    #pragma unroll
    for (int n = 0; n < 8; ++n) acc[n] = (float4v){0.f, 0.f, 0.f, 0.f};
    #pragma unroll
    for (int s = 0; s < 8; ++s) {
        short8v hv = H1[(size_t)jac * 32 + s * 4 + grp];
        int kb = s * 32 + grp * 8;
        short8v af;
        #pragma unroll
        for (int i = 0; i < 8; ++i) {
            float v = fmaf(bs2f(hv[i]), sA[kb + i], sB[kb + i]);
            af[i] = f2bs(fmaxf(v, 0.f));
        }
        #pragma unroll
        for (int n = 0; n < 8; ++n) {
            acc[n] = __builtin_amdgcn_mfma_f32_16x16x32_bf16(af, M2[(s * 8 + n) * 64 + l], acc[n], 0, 0, 0);
        }
    }
    float scl = lds_scalar(scale_p, bf);
    #pragma unroll
    for (int reg = 0; reg < 4; ++reg) {
        int jd = n0 + grp * 4 + reg;
        int jdc = jd < N ? jd : N - 1;
        float h[8];
        float ss = 0.f;
        #pragma unroll
        for (int n = 0; n < 8; ++n) {
            h[n] = acc[n][reg] + ldf(b_m2, n * 16 + row, bf);
            ss = fmaf(h[n], h[n], ss);
        }
        #pragma unroll
        for (int off = 1; off < 16; off <<= 1) ss += __shfl_xor(ss, off, 64);
        float hs = ws[OFF_XN + jdc] * scl / fmaxf(sqrtf(ss), 1e-12f);
        float y[8];
        float s1 = 0.f;
        #pragma unroll
        for (int n = 0; n < 8; ++n) {
            y[n] = ldf(x, (size_t)jdc * 128 + n * 16 + row, bf) + h[n] * hs;
            s1 += y[n];
        }
        #pragma unroll
        for (int off = 1; off < 16; off <<= 1) s1 += __shfl_xor(s1, off, 64);
        float mu = s1 * (1.f / 128.f);
        float s2 = 0.f;
        #pragma unroll
        for (int n = 0; n < 8; ++n) { float d = y[n] - mu; s2 = fmaf(d, d, s2); }
        #pragma unroll
        for (int off = 1; off < 16; off <<= 1) s2 += __shfl_xor(s2, off, 64);
        float rstd = rsqrtf(s2 * (1.f / 128.f) + 1e-5f);
        if (jd < N) {
            #pragma unroll
            for (int n = 0; n < 8; ++n) {
                int col = n * 16 + row;
                float o = (y[n] - mu) * rstd * ldf(g_n, col, bf) + ldf(b_n, col, bf);
                stf(x_out, (size_t)jd * 128 + col, o, bf);
            }
        }
    }
}

// ---------------- launcher ----------------

extern "C" void kernel_launch(void* const* d_in, const int* in_sizes, int n_in,
                              void* d_out, int out_size, void* d_ws, size_t ws_size,
                              hipStream_t stream) {
    const void* x    = d_in[0];
    const void* ea   = d_in[1];
    const int*  ei   = (const int*)d_in[2];
    const void* W_e  = d_in[3];
    const void* b_e  = d_in[4];
    const void* g_e  = d_in[5];
    const void* be_e = d_in[6];
    const void* t_p  = d_in[7];
    const void* W_m1 = d_in[8];
    const void* b_m1 = d_in[9];
    const void* g_bn = d_in[10];
    const void* b_bn = d_in[11];
    const void* W_m2 = d_in[12];
    const void* b_m2 = d_in[13];
    const void* scl  = d_in[14];
    const void* g_n  = d_in[15];
    const void* b_n  = d_in[16];

    float* ws = (float*)d_ws;
    bool big = ws_size >= WS_FLOATS_BIG * sizeof(float);

    k_detect<<<1, 256, 0, stream>>>((const unsigned short*)x, ws);
    k_init<<<512, 256, 0, stream>>>(ws, W_e, W_m1, W_m2);
    k_count<<<(E + 255) / 256, 256, 0, stream>>>(ei, ws);
    k_scan<<<1, 256, 0, stream>>>(ws);
    k_node_pre_mfma<<<NBLK, 256, 0, stream>>>(x, b_e, ws);
    if (big) {
        k_edge1_mfma<1><<<(E + 63) / 64, 256, 0, stream>>>(ea, ei, g_e, be_e, x, ws, d_out);
        k_agg_stream<<<N, 256, 0, stream>>>(x, t_p, ws);
    } else {
        k_edge1_mfma<0><<<(E + 63) / 64, 256, 0, stream>>>(ea, ei, g_e, be_e, x, ws, d_out);
        k_scatter<<<(E + 255) / 256, 256, 0, stream>>>(ei, ws);
        k_agg_gather<<<N, 256, 0, stream>>>(x, ei, t_p, d_out, ws);
    }
    k_h1_mfma<<<NBLK, 256, 0, stream>>>(b_m1, ws);
    k_bnstats<<<256, 256, 0, stream>>>(ws);
    k_node_post_mfma<<<NBLK, 256, 0, stream>>>(x, g_bn, b_bn, b_m2, scl, g_n, b_n, ws, d_out);
}

// Round 6
// 560.013 us; speedup vs baseline: 2.3210x; 1.0795x over previous
//
#include <hip/hip_runtime.h>
#include <hip/hip_bf16.h>

typedef __hip_bfloat16 bf16;
typedef __attribute__((ext_vector_type(8))) short short8v;   // 8 bf16 (4 VGPRs)
typedef __attribute__((ext_vector_type(4))) short short4v;   // 4 bf16 (8B)
typedef __attribute__((ext_vector_type(4))) float float4v;   // MFMA acc / 16B vec

constexpr int N = 25000;
constexpr int E = 250000;
constexpr size_t NB = (size_t)N * 128;            // 3,200,000
constexpr int NBLK = (N + 63) / 64;               // 391 node-tiles of 64

constexpr size_t al256(size_t x) { return (x + 255) / 256 * 256; }

// Workspace layout (float element offsets).
constexpr size_t OFF_BNS  = 0;                    // 256 f32 BN col sums
constexpr size_t OFF_BNQ  = OFF_BNS + 256;        // 256 f32 BN col sumsq
constexpr size_t OFF_FLAG = OFF_BNQ + 256;        // dtype flag (int in slot 0)
constexpr size_t OFF_XN   = OFF_FLAG + 256;       // N f32 ||x|| per row
constexpr size_t OFF_WB   = al256(OFF_XN + N);    // W3   bf16 frag-packed 16384 (8192 f32)
constexpr size_t OFF_WP   = OFF_WB + 8192;        // W1|W2 bf16 frag-packed 32768 (16384 f32)
constexpr size_t OFF_WM1P = OFF_WP + 16384;       // W_m1 bf16 frag-packed 32768
constexpr size_t OFF_WM2P = OFF_WM1P + 16384;     // W_m2 bf16 frag-packed 32768
constexpr size_t OFF_DEG  = al256(OFF_WM2P + 16384); // int[N] in-degree
constexpr size_t OFF_OFFS = al256(OFF_DEG + N);   // int[N+1] CSR offsets
constexpr size_t OFF_CUR  = al256(OFF_OFFS + N + 1); // int[N] cursors
constexpr size_t OFF_LIST = al256(OFF_CUR + N);   // int[E] edge ids by dest
constexpr size_t OFF_OUT  = al256(OFF_LIST + E);  // out = agg+x, N*128 bf16 (NB/2 f32)
constexpr size_t OFF_A    = al256(OFF_OUT + NB / 2);
// Region A: NB f32 slots (= 2*NB bf16), reused twice:
//   phase 1: XA [0,NB) bf16 | XB [NB,2NB) bf16
//   phase 2: H1 [0,2NB) bf16 (N x 256) overlays XA|XB
constexpr size_t WS_FLOATS = OFF_A + NB;          // ~21 MB (fallback footprint)
// Big path: MSG = E x 128 bf16 in EDGE order (64 MB), appended past region A.
constexpr size_t OFF_MSG  = al256(OFF_A + NB);    // E*64 f32 slots
constexpr size_t WS_FLOATS_BIG = OFF_MSG + (size_t)E * 64;   // ~85 MB

// ---------------- dtype-agnostic access ----------------

__device__ __forceinline__ float b2f(bf16 v) { return __bfloat162float(v); }
__device__ __forceinline__ short f2bs(float f) {
    bf16 h = __float2bfloat16(f);
    return *reinterpret_cast<short*>(&h);
}
__device__ __forceinline__ float bs2f(short s) {
    bf16 h;
    *reinterpret_cast<short*>(&h) = s;
    return b2f(h);
}

__device__ __forceinline__ float ldf(const void* p, size_t i, int bf) {
    return bf ? b2f(((const bf16*)p)[i]) : ((const float*)p)[i];
}
__device__ __forceinline__ void stf(void* p, size_t i, float v, int bf) {
    if (bf) ((bf16*)p)[i] = __float2bfloat16(v);
    else    ((float*)p)[i] = v;
}
__device__ __forceinline__ void stf_nt(void* p, size_t i, float v, int bf) {
    if (bf) __builtin_nontemporal_store(f2bs(v), (short*)p + i);
    else    __builtin_nontemporal_store(v, (float*)p + i);
}
__device__ __forceinline__ float4v load4(const void* p, size_t i, int bf) {
    if (bf) {
        short4v s = *(const short4v*)((const bf16*)p + i);
        return (float4v){bs2f(s[0]), bs2f(s[1]), bs2f(s[2]), bs2f(s[3])};
    }
    return *(const float4v*)((const float*)p + i);
}
__device__ __forceinline__ void store4_nt(void* p, size_t i, float4v v, int bf) {
    if (bf) {
        short4v s = {f2bs(v[0]), f2bs(v[1]), f2bs(v[2]), f2bs(v[3])};
        __builtin_nontemporal_store(s, (short4v*)((bf16*)p + i));
    } else {
        __builtin_nontemporal_store(v, (float4v*)((float*)p + i));
    }
}
__device__ __forceinline__ float lds_scalar(const void* p, int bf) {
    if (!bf) return *(const float*)p;
    float v = b2f(*(const bf16*)p);
    float a = fabsf(v);
    return (a >= 0.0009765625f && a <= 1024.0f) ? v : *(const float*)p;
}
__device__ __forceinline__ int get_flag(const float* ws) {
    return *(const int*)(ws + OFF_FLAG);
}
__device__ __forceinline__ void* e_base(void* d_out, int bf) {
    return bf ? (void*)((bf16*)d_out + NB) : (void*)((float*)d_out + NB);
}

// ---------------- kernels ----------------

// Detect element dtype of x; zero BN accumulators and degree counts.
__global__ void k_detect(const unsigned short* __restrict__ xu, float* __restrict__ ws) {
    __shared__ int cnt;
    if (threadIdx.x == 0) cnt = 0;
    __syncthreads();
    int c = 0;
    for (int i = threadIdx.x; i < 512; i += 256) {
        unsigned e = (xu[i] >> 7) & 0xFFu;
        if (e >= 110u && e <= 135u) c++;
    }
    atomicAdd(&cnt, c);
    for (int i = threadIdx.x; i < 512; i += 256) ws[OFF_BNS + i] = 0.0f;
    int* deg = (int*)(ws + OFF_DEG);
    for (int i = threadIdx.x; i < N; i += 256) deg[i] = 0;
    __syncthreads();
    if (threadIdx.x == 0) *(int*)(ws + OFF_FLAG) = (cnt >= 460) ? 1 : 0;
}

// Pack all weights into bf16 MFMA-fragment order (COALESCED source reads,
// scattered bf16 writes via the inverse fragment map) and count in-degrees.
// Forward map (verified round 2): t -> k = s*32+(l>>4)*8+i, c = n*16+(l&15).
// Inverse: t(k,c) = s*(NN*512) + (c>>4)*512 + (((k&31)>>3)*16 + (c&15))*8 + (k&7).
__global__ void k_init(float* __restrict__ ws, const void* __restrict__ W_e,
                       const void* __restrict__ W_m1, const void* __restrict__ W_m2,
                       const int* __restrict__ ei) {
    int bf = get_flag(ws);
    size_t gid = (size_t)blockIdx.x * blockDim.x + threadIdx.x;
    size_t stride = (size_t)gridDim.x * blockDim.x;
    short* WB = (short*)(ws + OFF_WB);
    for (size_t u = gid; u < 16384; u += stride) {
        int k = u >> 7, c = u & 127;
        int t = (k >> 5) * 4096 + (c >> 4) * 512 + (((k & 31) >> 3) * 16 + (c & 15)) * 8 + (k & 7);
        WB[t] = f2bs(ldf(W_e, (size_t)(256 + k) * 128 + c, bf));
    }
    short* WP = (short*)(ws + OFF_WP);
    for (size_t u = gid; u < 32768; u += stride) {
        int k = u >> 8, c = u & 255;
        int t = (k >> 5) * 8192 + (c >> 4) * 512 + (((k & 31) >> 3) * 16 + (c & 15)) * 8 + (k & 7);
        float v = (c < 128) ? ldf(W_e, (size_t)k * 128 + c, bf)
                            : ldf(W_e, (size_t)(128 + k) * 128 + (c - 128), bf);
        WP[t] = f2bs(v);
    }
    short* M1 = (short*)(ws + OFF_WM1P);
    for (size_t u = gid; u < 32768; u += stride) {
        int k = u >> 8, c = u & 255;
        int t = (k >> 5) * 8192 + (c >> 4) * 512 + (((k & 31) >> 3) * 16 + (c & 15)) * 8 + (k & 7);
        M1[t] = f2bs(ldf(W_m1, (size_t)k * 256 + c, bf));
    }
    short* M2 = (short*)(ws + OFF_WM2P);
    for (size_t u = gid; u < 32768; u += stride) {
        int k = u >> 7, c = u & 127;
        int t = (k >> 5) * 4096 + (c >> 4) * 512 + (((k & 31) >> 3) * 16 + (c & 15)) * 8 + (k & 7);
        M2[t] = f2bs(ldf(W_m2, (size_t)k * 128 + c, bf));
    }
    int* deg = (int*)(ws + OFF_DEG);
    for (size_t j = gid; j < E; j += stride) atomicAdd(deg + ei[E + j], 1);
}

// Per 64 nodes (4 waves x 16 rows): [xa|xb] = x @ WP (+b_e on xa), bf16 -> XA|XB.
// Also row ||x|| from the A-fragment values.
__global__ __launch_bounds__(256) void k_node_pre_mfma(const void* __restrict__ x,
                                                       const void* __restrict__ b_e,
                                                       float* __restrict__ ws) {
    int bf = get_flag(ws);
    int l = threadIdx.x & 63, wv = threadIdx.x >> 6;
    int n0 = blockIdx.x * 64 + wv * 16;
    if (n0 >= N) return;
    int row = l & 15, grp = l >> 4;
    int ja = n0 + row;
    int jac = ja < N ? ja : N - 1;
    const short8v* WP = (const short8v*)(ws + OFF_WP);
    float4v acc[16];
    #pragma unroll
    for (int n = 0; n < 16; ++n) acc[n] = (float4v){0.f, 0.f, 0.f, 0.f};
    float sq = 0.f;
    #pragma unroll
    for (int s = 0; s < 4; ++s) {
        short8v af;
        if (bf) {
            af = ((const short8v*)x)[(size_t)jac * 16 + s * 4 + grp];
            #pragma unroll
            for (int i = 0; i < 8; ++i) { float v = bs2f(af[i]); sq = fmaf(v, v, sq); }
        } else {
            const float* er = (const float*)x + (size_t)jac * 128 + s * 32 + grp * 8;
            float4v lo = *(const float4v*)er;
            float4v hi = *(const float4v*)(er + 4);
            float xv[8] = {lo[0], lo[1], lo[2], lo[3], hi[0], hi[1], hi[2], hi[3]};
            #pragma unroll
            for (int i = 0; i < 8; ++i) { sq = fmaf(xv[i], xv[i], sq); af[i] = f2bs(xv[i]); }
        }
        #pragma unroll
        for (int n = 0; n < 16; ++n) {
            acc[n] = __builtin_amdgcn_mfma_f32_16x16x32_bf16(af, WP[(s * 16 + n) * 64 + l], acc[n], 0, 0, 0);
        }
    }
    sq += __shfl_xor(sq, 16, 64);
    sq += __shfl_xor(sq, 32, 64);
    if (grp == 0 && ja < N) ws[OFF_XN + ja] = sqrtf(sq);
    bf16* XA = (bf16*)(ws + OFF_A);
    #pragma unroll
    for (int reg = 0; reg < 4; ++reg) {
        int jd = n0 + grp * 4 + reg;
        if (jd >= N) continue;
        #pragma unroll
        for (int n = 0; n < 16; ++n) {
            int c = n * 16 + row;
            if (n < 8) {
                XA[(size_t)jd * 128 + c] = __float2bfloat16(acc[n][reg] + ldf(b_e, c, bf));
            } else {
                XA[NB + (size_t)jd * 128 + (c - 128)] = __float2bfloat16(acc[n][reg]);
            }
        }
    }
}

// Per-edge MLP via MFMA, operand-swapped (D[ch][edge]): lane owns one edge
// (eq = l&15) x 32 channels (ch = m*16 + grp*4 + w).
//   pre = XA[r] + XB[cd] + ea @ W3;  e = LN(relu(pre)) * g + b + ea
// WM: also write msg = relu(x[r]+e)+eps as bf16 into MSG[edge] (CONTIGUOUS).
// XA/XB gather rows are prefetched BEFORE the GEMM to hide latency under MFMA.
template<int WM>
__global__ __launch_bounds__(256) void k_edge1_mfma(const void* __restrict__ ea,
                                                    const int* __restrict__ ei,
                                                    const void* __restrict__ g_e,
                                                    const void* __restrict__ be_e,
                                                    const void* __restrict__ x,
                                                    float* __restrict__ ws,
                                                    void* __restrict__ d_out) {
    int bf = get_flag(ws);
    void* eo = e_base(d_out, bf);
    int l = threadIdx.x & 63;
    int wv = threadIdx.x >> 6;
    int e0w = blockIdx.x * 64 + wv * 16;
    if (e0w >= E) return;
    int eq = l & 15, grp = l >> 4;

    int j = e0w + eq;
    bool valid = j < E;
    int jc = valid ? j : E - 1;
    int r = ei[jc], cd = ei[E + jc];

    // ---- prefetch epilogue gathers (independent of GEMM) ----
    const bf16* XAp = (const bf16*)(ws + OFF_A);
    short4v xa[8], xb[8];
    #pragma unroll
    for (int m = 0; m < 8; ++m) {
        int ch = m * 16 + grp * 4;
        xa[m] = *(const short4v*)(XAp + (size_t)r * 128 + ch);
        xb[m] = *(const short4v*)(XAp + NB + (size_t)cd * 128 + ch);
    }

    // ---- GEMM: acc[m] = W3_frag(A) x ea_frag(B) -> D[ch][edge] ----
    const short8v* WB = (const short8v*)(ws + OFF_WB);
    float4v acc[8];
    #pragma unroll
    for (int m = 0; m < 8; ++m) acc[m] = (float4v){0.f, 0.f, 0.f, 0.f};

    #pragma unroll
    for (int s = 0; s < 4; ++s) {
        short8v bfr;   // B-fragment: ea[jc][s*32 + grp*8 + i]
        if (bf) {
            bfr = ((const short8v*)ea)[(size_t)jc * 16 + s * 4 + grp];
        } else {
            const float* er = (const float*)ea + (size_t)jc * 128 + s * 32 + grp * 8;
            float4v lo = *(const float4v*)er;
            float4v hi = *(const float4v*)(er + 4);
            bfr[0] = f2bs(lo[0]); bfr[1] = f2bs(lo[1]); bfr[2] = f2bs(lo[2]); bfr[3] = f2bs(lo[3]);
            bfr[4] = f2bs(hi[0]); bfr[5] = f2bs(hi[1]); bfr[6] = f2bs(hi[2]); bfr[7] = f2bs(hi[3]);
        }
        #pragma unroll
        for (int m = 0; m < 8; ++m) {
            acc[m] = __builtin_amdgcn_mfma_f32_16x16x32_bf16(WB[(s * 8 + m) * 64 + l], bfr, acc[m], 0, 0, 0);
        }
    }

    // ---- epilogue ----
    float p[8][4];
    float s1 = 0.f, s2 = 0.f;
    #pragma unroll
    for (int m = 0; m < 8; ++m) {
        #pragma unroll
        for (int w = 0; w < 4; ++w) {
            float v = acc[m][w] + bs2f(xa[m][w]) + bs2f(xb[m][w]);
            v = fmaxf(v, 0.f);
            p[m][w] = v;
            s1 += v;
            s2 = fmaf(v, v, s2);
        }
    }
    // issue x gathers (needed for msg) before the shuffle chain
    float4v xr[8];
    if (WM) {
        #pragma unroll
        for (int m = 0; m < 8; ++m) xr[m] = load4(x, (size_t)r * 128 + m * 16 + grp * 4, bf);
    }
    s1 += __shfl_xor(s1, 16, 64);
    s1 += __shfl_xor(s1, 32, 64);
    s2 += __shfl_xor(s2, 16, 64);
    s2 += __shfl_xor(s2, 32, 64);
    float mu = s1 * (1.f / 128.f);
    float var = s2 * (1.f / 128.f) - mu * mu;
    float rstd = rsqrtf(fmaxf(var, 0.f) + 1e-5f);

    bf16* MSG = (bf16*)(ws + OFF_MSG);
    #pragma unroll
    for (int m = 0; m < 8; ++m) {
        int ch = m * 16 + grp * 4;
        float4v gg = load4(g_e, ch, bf);
        float4v bb = load4(be_e, ch, bf);
        float4v eav = load4(ea, (size_t)jc * 128 + ch, bf);
        float4v ev;
        #pragma unroll
        for (int w = 0; w < 4; ++w)
            ev[w] = (p[m][w] - mu) * rstd * gg[w] + bb[w] + eav[w];
        if (valid) store4_nt(eo, (size_t)j * 128 + ch, ev, bf);
        if (WM && valid) {
            short4v ms;
            #pragma unroll
            for (int w = 0; w < 4; ++w)
                ms[w] = f2bs(fmaxf(xr[m][w] + ev[w], 0.f) + 1e-7f);
            *(short4v*)(MSG + (size_t)j * 128 + ch) = ms;
        }
    }
}

// Exclusive scan of degree counts -> CSR offsets + scatter cursors. 1 block.
__global__ __launch_bounds__(256) void k_scan(float* __restrict__ ws) {
    const int* deg = (const int*)(ws + OFF_DEG);
    int* offs = (int*)(ws + OFF_OFFS);
    int* cur  = (int*)(ws + OFF_CUR);
    __shared__ int sums[256];
    __shared__ int carry[257];
    int t = threadIdx.x;
    const int chunk = (N + 255) / 256;
    int lo = t * chunk, hi = lo + chunk < N ? lo + chunk : N;
    int s = 0;
    for (int i = lo; i < hi; ++i) s += deg[i];
    sums[t] = s;
    __syncthreads();
    if (t == 0) {
        int acc = 0;
        #pragma unroll 4
        for (int i = 0; i < 256; ++i) { carry[i] = acc; acc += sums[i]; }
        carry[256] = acc;
    }
    __syncthreads();
    int acc = carry[t];
    for (int i = lo; i < hi; ++i) { offs[i] = acc; cur[i] = acc; acc += deg[i]; }
    if (t == 0) offs[N] = carry[256];
}

// Scatter edge ids into CSR list by destination.
__global__ void k_scatter(const int* __restrict__ ei, float* __restrict__ ws) {
    int j = blockIdx.x * blockDim.x + threadIdx.x;
    if (j >= E) return;
    int cd = ei[E + j];
    int pos = atomicAdd((int*)(ws + OFF_CUR) + cd, 1);
    ((int*)(ws + OFF_LIST))[pos] = j;
}

// Big path: per node, gather MSG rows via LIST (16-edge-parallel x 8-channel
// vector loads), softmax-aggregate (fixed-shift exp; shift-invariant;
// msg includes +eps). out = agg + x -> OUT bf16.
__global__ __launch_bounds__(256) void k_agg_stream(const void* __restrict__ x,
                                                    const void* __restrict__ t_p,
                                                    float* __restrict__ ws) {
    int bf = get_flag(ws);
    int n = blockIdx.x, tid = threadIdx.x;
    int par = tid >> 4;          // 0..15 edge-parallel
    int cg = tid & 15;           // channel group: ch = cg*8 .. +8
    const int* offs = (const int*)(ws + OFF_OFFS);
    const int* list = (const int*)(ws + OFF_LIST);
    int s0 = offs[n], s1v = offs[n + 1];
    float t = lds_scalar(t_p, bf);
    const short8v* MSG = (const short8v*)((const bf16*)(ws + OFF_MSG));
    float den[8], num[8];
    #pragma unroll
    for (int w = 0; w < 8; ++w) { den[w] = 0.f; num[w] = 0.f; }
    for (int i = s0 + par; i < s1v; i += 16) {
        int jj = list[i];
        short8v m8 = MSG[(size_t)jj * 16 + cg];
        #pragma unroll
        for (int w = 0; w < 8; ++w) {
            float m = bs2f(m8[w]);
            float ex = __expf(fmaf(m, t, -15.0f));
            den[w] += ex;
            num[w] = fmaf(m, ex, num[w]);
        }
    }
    __shared__ float sd[16][132];
    __shared__ float sn[16][132];
    #pragma unroll
    for (int w = 0; w < 8; ++w) { sd[par][cg * 8 + w] = den[w]; sn[par][cg * 8 + w] = num[w]; }
    __syncthreads();
    if (tid < 128) {
        float dn = 0.f, nm = 0.f;
        #pragma unroll
        for (int p = 0; p < 16; ++p) { dn += sd[p][tid]; nm += sn[p][tid]; }
        float ag = dn > 0.f ? nm / dn : 0.f;
        float out = ag + ldf(x, (size_t)n * 128 + tid, bf);
        ((bf16*)(ws + OFF_OUT))[(size_t)n * 128 + tid] = __float2bfloat16(out);
    }
}

// Fallback: gather incident edges via LIST, recompute msg from e and x.
__global__ __launch_bounds__(256) void k_agg_gather(const void* __restrict__ x,
                                                    const int* __restrict__ ei,
                                                    const void* __restrict__ t_p,
                                                    void* __restrict__ d_out,
                                                    float* __restrict__ ws) {
    int bf = get_flag(ws);
    const void* e_in = e_base(d_out, bf);
    int n = blockIdx.x, tid = threadIdx.x;
    int c = tid & 127, half = tid >> 7;
    const int* offs = (const int*)(ws + OFF_OFFS);
    const int* list = (const int*)(ws + OFF_LIST);
    int s0 = offs[n], s1v = offs[n + 1];
    float t = lds_scalar(t_p, bf);
    float den = 0.f, num = 0.f;
    for (int i = s0 + half; i < s1v; i += 2) {
        int j = list[i];
        int r = ei[j];
        float ev = ldf(e_in, (size_t)j * 128 + c, bf);
        float msg = fmaxf(ldf(x, (size_t)r * 128 + c, bf) + ev, 0.f) + 1e-7f;
        float ex = expf(msg * t - 15.0f);
        den += ex;
        num = fmaf(msg, ex, num);
    }
    __shared__ float dsh[256];
    __shared__ float nsh[256];
    dsh[tid] = den;
    nsh[tid] = num;
    __syncthreads();
    if (tid < 128) {
        float dn = dsh[tid] + dsh[tid + 128];
        float nm = nsh[tid] + nsh[tid + 128];
        float ag = dn > 0.f ? nm / dn : 0.f;
        float out = ag + ldf(x, (size_t)n * 128 + tid, bf);
        ((bf16*)(ws + OFF_OUT))[(size_t)n * 128 + tid] = __float2bfloat16(out);
    }
}

// H1 = out @ W_m1 + b_m1 (bf16, N x 256), 64 nodes per block,
// with FUSED BatchNorm column sums/sumsq (shfl + LDS + global atomics).
// No early returns: all waves reach the barrier.
__global__ __launch_bounds__(256) void k_h1_mfma(const void* __restrict__ b_m1,
                                                 float* __restrict__ ws) {
    int bf = get_flag(ws);
    int l = threadIdx.x & 63, wv = threadIdx.x >> 6;
    int n0 = blockIdx.x * 64 + wv * 16;
    int row = l & 15, grp = l >> 4;
    int ja = n0 + row;
    int jac = ja < N ? ja : N - 1;
    const short8v* OUT = (const short8v*)(ws + OFF_OUT);
    const short8v* M1 = (const short8v*)(ws + OFF_WM1P);
    float4v acc[16];
    #pragma unroll
    for (int n = 0; n < 16; ++n) acc[n] = (float4v){0.f, 0.f, 0.f, 0.f};
    #pragma unroll
    for (int s = 0; s < 4; ++s) {
        short8v af = OUT[(size_t)jac * 16 + s * 4 + grp];
        #pragma unroll
        for (int n = 0; n < 16; ++n) {
            acc[n] = __builtin_amdgcn_mfma_f32_16x16x32_bf16(af, M1[(s * 16 + n) * 64 + l], acc[n], 0, 0, 0);
        }
    }
    __shared__ float sds[4][264];
    __shared__ float sqs[4][264];
    bf16* H1 = (bf16*)(ws + OFF_A);
    #pragma unroll
    for (int n = 0; n < 16; ++n) {
        int col = n * 16 + row;
        float bias = ldf(b_m1, col, bf);
        float vs = 0.f, vq = 0.f;
        #pragma unroll
        for (int reg = 0; reg < 4; ++reg) {
            int jd = n0 + grp * 4 + reg;
            float v = acc[n][reg] + bias;
            if (jd < N) {
                H1[(size_t)jd * 256 + col] = __float2bfloat16(v);
                vs += v;
                vq = fmaf(v, v, vq);
            }
        }
        vs += __shfl_xor(vs, 16, 64); vs += __shfl_xor(vs, 32, 64);
        vq += __shfl_xor(vq, 16, 64); vq += __shfl_xor(vq, 32, 64);
        if (grp == 0) { sds[wv][col] = vs; sqs[wv][col] = vq; }
    }
    __syncthreads();
    int t = threadIdx.x;
    if (t < 256) {
        float s = sds[0][t] + sds[1][t] + sds[2][t] + sds[3][t];
        float q = sqs[0][t] + sqs[1][t] + sqs[2][t] + sqs[3][t];
        atomicAdd(&ws[OFF_BNS + t], s);
        atomicAdd(&ws[OFF_BNQ + t], q);
    }
}

// Per 64 nodes: hbn = relu(BN(H1)) built in-register as A-fragment;
// h = hbn @ W_m2 + b_m2; MessageNorm; residual + LayerNorm -> x_out.
__global__ __launch_bounds__(256) void k_node_post_mfma(const void* __restrict__ x,
                                                        const void* __restrict__ g_bn,
                                                        const void* __restrict__ b_bn,
                                                        const void* __restrict__ b_m2,
                                                        const void* __restrict__ scale_p,
                                                        const void* __restrict__ g_n,
                                                        const void* __restrict__ b_n,
                                                        float* __restrict__ ws,
                                                        void* __restrict__ x_out) {
    int bf = get_flag(ws);
    __shared__ float sA[256];   // per-col BN scale = rstd*g
    __shared__ float sB[256];   // per-col BN shift = b - mu*rstd*g
    {
        int t = threadIdx.x;
        const float inv_n = 1.f / (float)N;
        float mu = ws[OFF_BNS + t] * inv_n;
        float var = ws[OFF_BNQ + t] * inv_n - mu * mu;
        float rs = rsqrtf(fmaxf(var, 0.f) + 1e-5f) * ldf(g_bn, t, bf);
        sA[t] = rs;
        sB[t] = ldf(b_bn, t, bf) - mu * rs;
    }
    __syncthreads();
    int l = threadIdx.x & 63, wv = threadIdx.x >> 6;
    int n0 = blockIdx.x * 64 + wv * 16;
    if (n0 >= N) return;   // after the only barrier — safe
    int row = l & 15, grp = l >> 4;
    int ja = n0 + row;
    int jac = ja < N ? ja : N - 1;
    const short8v* H1 = (const short8v*)(ws + OFF_A);
    const short8v* M2 = (const short8v*)(ws + OFF_WM2P);
    float4v acc[8];
    #pragma unroll
    for (int n = 0; n < 8; ++n) acc[n] = (float4v){0.f, 0.f, 0.f, 0.f};
    #pragma unroll
    for (int s = 0; s < 8; ++s) {
        short8v hv = H1[(size_t)jac * 32 + s * 4 + grp];
        int kb = s * 32 + grp * 8;
        short8v af;
        #pragma unroll
        for (int i = 0; i < 8; ++i) {
            float v = fmaf(bs2f(hv[i]), sA[kb + i], sB[kb + i]);
            af[i] = f2bs(fmaxf(v, 0.f));
        }
        #pragma unroll
        for (int n = 0; n < 8; ++n) {
            acc[n] = __builtin_amdgcn_mfma_f32_16x16x32_bf16(af, M2[(s * 8 + n) * 64 + l], acc[n], 0, 0, 0);
        }
    }
    float scl = lds_scalar(scale_p, bf);
    #pragma unroll
    for (int reg = 0; reg < 4; ++reg) {
        int jd = n0 + grp * 4 + reg;
        int jdc = jd < N ? jd : N - 1;
        float h[8];
        float ss = 0.f;
        #pragma unroll
        for (int n = 0; n < 8; ++n) {
            h[n] = acc[n][reg] + ldf(b_m2, n * 16 + row, bf);
            ss = fmaf(h[n], h[n], ss);
        }
        #pragma unroll
        for (int off = 1; off < 16; off <<= 1) ss += __shfl_xor(ss, off, 64);
        float hs = ws[OFF_XN + jdc] * scl / fmaxf(sqrtf(ss), 1e-12f);
        float y[8];
        float s1 = 0.f;
        #pragma unroll
        for (int n = 0; n < 8; ++n) {
            y[n] = ldf(x, (size_t)jdc * 128 + n * 16 + row, bf) + h[n] * hs;
            s1 += y[n];
        }
        #pragma unroll
        for (int off = 1; off < 16; off <<= 1) s1 += __shfl_xor(s1, off, 64);
        float mu = s1 * (1.f / 128.f);
        float s2 = 0.f;
        #pragma unroll
        for (int n = 0; n < 8; ++n) { float d = y[n] - mu; s2 = fmaf(d, d, s2); }
        #pragma unroll
        for (int off = 1; off < 16; off <<= 1) s2 += __shfl_xor(s2, off, 64);
        float rstd = rsqrtf(s2 * (1.f / 128.f) + 1e-5f);
        if (jd < N) {
            #pragma unroll
            for (int n = 0; n < 8; ++n) {
                int col = n * 16 + row;
                float o = (y[n] - mu) * rstd * ldf(g_n, col, bf) + ldf(b_n, col, bf);
                stf_nt(x_out, (size_t)jd * 128 + col, o, bf);
            }
        }
    }
}

// ---------------- launcher ----------------

extern "C" void kernel_launch(void* const* d_in, const int* in_sizes, int n_in,
                              void* d_out, int out_size, void* d_ws, size_t ws_size,
                              hipStream_t stream) {
    const void* x    = d_in[0];
    const void* ea   = d_in[1];
    const int*  ei   = (const int*)d_in[2];
    const void* W_e  = d_in[3];
    const void* b_e  = d_in[4];
    const void* g_e  = d_in[5];
    const void* be_e = d_in[6];
    const void* t_p  = d_in[7];
    const void* W_m1 = d_in[8];
    const void* b_m1 = d_in[9];
    const void* g_bn = d_in[10];
    const void* b_bn = d_in[11];
    const void* W_m2 = d_in[12];
    const void* b_m2 = d_in[13];
    const void* scl  = d_in[14];
    const void* g_n  = d_in[15];
    const void* b_n  = d_in[16];

    float* ws = (float*)d_ws;
    bool big = ws_size >= WS_FLOATS_BIG * sizeof(float);

    k_detect<<<1, 256, 0, stream>>>((const unsigned short*)x, ws);
    k_init<<<512, 256, 0, stream>>>(ws, W_e, W_m1, W_m2, ei);
    k_scan<<<1, 256, 0, stream>>>(ws);
    k_scatter<<<(E + 255) / 256, 256, 0, stream>>>(ei, ws);
    k_node_pre_mfma<<<NBLK, 256, 0, stream>>>(x, b_e, ws);
    if (big) {
        k_edge1_mfma<1><<<(E + 63) / 64, 256, 0, stream>>>(ea, ei, g_e, be_e, x, ws, d_out);
        k_agg_stream<<<N, 256, 0, stream>>>(x, t_p, ws);
    } else {
        k_edge1_mfma<0><<<(E + 63) / 64, 256, 0, stream>>>(ea, ei, g_e, be_e, x, ws, d_out);
        k_agg_gather<<<N, 256, 0, stream>>>(x, ei, t_p, d_out, ws);
    }
    k_h1_mfma<<<NBLK, 256, 0, stream>>>(b_m1, ws);
    k_node_post_mfma<<<NBLK, 256, 0, stream>>>(x, g_bn, b_bn, b_m2, scl, g_n, b_n, ws, d_out);
}

// Round 7
// 521.098 us; speedup vs baseline: 2.4943x; 1.0747x over previous
//
#include <hip/hip_runtime.h>
#include <hip/hip_bf16.h>

typedef __hip_bfloat16 bf16;
typedef __attribute__((ext_vector_type(8))) short short8v;   // 8 bf16 (4 VGPRs)
typedef __attribute__((ext_vector_type(4))) short short4v;   // 4 bf16 (8B)
typedef __attribute__((ext_vector_type(4))) float float4v;   // MFMA acc / 16B vec
typedef unsigned long long u64;

constexpr int N = 25000;
constexpr int E = 250000;
constexpr size_t NB = (size_t)N * 128;            // 3,200,000
constexpr int NBLK = (N + 63) / 64;               // 391 node-tiles of 64

constexpr size_t al256(size_t x) { return (x + 255) / 256 * 256; }

// Workspace layout (float element offsets). Total ~21 MB.
constexpr size_t OFF_BNS  = 0;                    // 256 f32 BN col sums
constexpr size_t OFF_BNQ  = OFF_BNS + 256;        // 256 f32 BN col sumsq
constexpr size_t OFF_FLAG = OFF_BNQ + 256;        // dtype flag (int in slot 0)
constexpr size_t OFF_XN   = OFF_FLAG + 256;       // N f32 ||x|| per row
constexpr size_t OFF_WB   = al256(OFF_XN + N);    // W3   bf16 frag-packed 16384 (8192 f32)
constexpr size_t OFF_WP   = OFF_WB + 8192;        // W1|W2 bf16 frag-packed 32768 (16384 f32)
constexpr size_t OFF_WM1P = OFF_WP + 16384;       // W_m1 bf16 frag-packed 32768
constexpr size_t OFF_WM2P = OFF_WM1P + 16384;     // W_m2 bf16 frag-packed 32768
constexpr size_t OFF_DEG  = al256(OFF_WM2P + 16384); // int[N] in-degree
constexpr size_t OFF_OFFS = al256(OFF_DEG + N);   // int[N+1] CSR offsets
constexpr size_t OFF_CUR  = al256(OFF_OFFS + N + 1); // int[N] cursors
constexpr size_t OFF_LIST = al256(OFF_CUR + N);   // int[E] edge ids by dest
constexpr size_t OFF_OUT  = al256(OFF_LIST + E);  // out = agg+x, N*128 bf16 (NB/2 f32)
constexpr size_t OFF_A    = al256(OFF_OUT + NB / 2);
// Region A: NB f32 slots (= 2*NB bf16), reused twice:
//   phase 1: XA [0,NB) bf16 | XB [NB,2NB) bf16
//   phase 2: H1 [0,2NB) bf16 (N x 256) overlays XA|XB
constexpr size_t WS_FLOATS = OFF_A + NB;

// ---------------- dtype-agnostic access ----------------

__device__ __forceinline__ float b2f(bf16 v) { return __bfloat162float(v); }
__device__ __forceinline__ short f2bs(float f) {
    bf16 h = __float2bfloat16(f);
    return *reinterpret_cast<short*>(&h);
}
__device__ __forceinline__ float bs2f(short s) {
    bf16 h;
    *reinterpret_cast<short*>(&h) = s;
    return b2f(h);
}

__device__ __forceinline__ float ldf(const void* p, size_t i, int bf) {
    return bf ? b2f(((const bf16*)p)[i]) : ((const float*)p)[i];
}
__device__ __forceinline__ void stf_nt(void* p, size_t i, float v, int bf) {
    if (bf) __builtin_nontemporal_store(f2bs(v), (short*)p + i);
    else    __builtin_nontemporal_store(v, (float*)p + i);
}
__device__ __forceinline__ float4v load4(const void* p, size_t i, int bf) {
    if (bf) {
        short4v s = *(const short4v*)((const bf16*)p + i);
        return (float4v){bs2f(s[0]), bs2f(s[1]), bs2f(s[2]), bs2f(s[3])};
    }
    return *(const float4v*)((const float*)p + i);
}
__device__ __forceinline__ void store4(void* p, size_t i, float4v v, int bf) {
    if (bf) {
        short4v s = {f2bs(v[0]), f2bs(v[1]), f2bs(v[2]), f2bs(v[3])};
        *(short4v*)((bf16*)p + i) = s;
    } else {
        *(float4v*)((float*)p + i) = v;
    }
}
__device__ __forceinline__ float lds_scalar(const void* p, int bf) {
    if (!bf) return *(const float*)p;
    float v = b2f(*(const bf16*)p);
    float a = fabsf(v);
    return (a >= 0.0009765625f && a <= 1024.0f) ? v : *(const float*)p;
}
__device__ __forceinline__ int get_flag(const float* ws) {
    return *(const int*)(ws + OFF_FLAG);
}
__device__ __forceinline__ void* e_base(void* d_out, int bf) {
    return bf ? (void*)((bf16*)d_out + NB) : (void*)((float*)d_out + NB);
}

// ---------------- kernels ----------------

// Detect element dtype of x; zero BN accumulators and degree counts.
__global__ void k_detect(const unsigned short* __restrict__ xu, float* __restrict__ ws) {
    __shared__ int cnt;
    if (threadIdx.x == 0) cnt = 0;
    __syncthreads();
    int c = 0;
    for (int i = threadIdx.x; i < 512; i += 256) {
        unsigned e = (xu[i] >> 7) & 0xFFu;
        if (e >= 110u && e <= 135u) c++;
    }
    atomicAdd(&cnt, c);
    for (int i = threadIdx.x; i < 512; i += 256) ws[OFF_BNS + i] = 0.0f;
    int* deg = (int*)(ws + OFF_DEG);
    for (int i = threadIdx.x; i < N; i += 256) deg[i] = 0;
    __syncthreads();
    if (threadIdx.x == 0) *(int*)(ws + OFF_FLAG) = (cnt >= 460) ? 1 : 0;
}

// Pack all weights into bf16 MFMA-fragment order (coalesced source reads,
// scattered bf16 writes via the inverse fragment map) and count in-degrees.
// Forward map (verified round 2): t -> k = s*32+(l>>4)*8+i, c = n*16+(l&15).
__global__ void k_init(float* __restrict__ ws, const void* __restrict__ W_e,
                       const void* __restrict__ W_m1, const void* __restrict__ W_m2,
                       const int* __restrict__ ei) {
    int bf = get_flag(ws);
    size_t gid = (size_t)blockIdx.x * blockDim.x + threadIdx.x;
    size_t stride = (size_t)gridDim.x * blockDim.x;
    short* WB = (short*)(ws + OFF_WB);
    for (size_t u = gid; u < 16384; u += stride) {
        int k = u >> 7, c = u & 127;
        int t = (k >> 5) * 4096 + (c >> 4) * 512 + (((k & 31) >> 3) * 16 + (c & 15)) * 8 + (k & 7);
        WB[t] = f2bs(ldf(W_e, (size_t)(256 + k) * 128 + c, bf));
    }
    short* WP = (short*)(ws + OFF_WP);
    for (size_t u = gid; u < 32768; u += stride) {
        int k = u >> 8, c = u & 255;
        int t = (k >> 5) * 8192 + (c >> 4) * 512 + (((k & 31) >> 3) * 16 + (c & 15)) * 8 + (k & 7);
        float v = (c < 128) ? ldf(W_e, (size_t)k * 128 + c, bf)
                            : ldf(W_e, (size_t)(128 + k) * 128 + (c - 128), bf);
        WP[t] = f2bs(v);
    }
    short* M1 = (short*)(ws + OFF_WM1P);
    for (size_t u = gid; u < 32768; u += stride) {
        int k = u >> 8, c = u & 255;
        int t = (k >> 5) * 8192 + (c >> 4) * 512 + (((k & 31) >> 3) * 16 + (c & 15)) * 8 + (k & 7);
        M1[t] = f2bs(ldf(W_m1, (size_t)k * 256 + c, bf));
    }
    short* M2 = (short*)(ws + OFF_WM2P);
    for (size_t u = gid; u < 32768; u += stride) {
        int k = u >> 7, c = u & 127;
        int t = (k >> 5) * 4096 + (c >> 4) * 512 + (((k & 31) >> 3) * 16 + (c & 15)) * 8 + (k & 7);
        M2[t] = f2bs(ldf(W_m2, (size_t)k * 128 + c, bf));
    }
    int* deg = (int*)(ws + OFF_DEG);
    for (size_t j = gid; j < E; j += stride) atomicAdd(deg + ei[E + j], 1);
}

// Per 64 nodes (4 waves x 16 rows): [xa|xb] = x @ WP (+b_e on xa), bf16 -> XA|XB.
// Also row ||x|| from the A-fragment values.
__global__ __launch_bounds__(256) void k_node_pre_mfma(const void* __restrict__ x,
                                                       const void* __restrict__ b_e,
                                                       float* __restrict__ ws) {
    int bf = get_flag(ws);
    int l = threadIdx.x & 63, wv = threadIdx.x >> 6;
    int n0 = blockIdx.x * 64 + wv * 16;
    if (n0 >= N) return;
    int row = l & 15, grp = l >> 4;
    int ja = n0 + row;
    int jac = ja < N ? ja : N - 1;
    const short8v* WP = (const short8v*)(ws + OFF_WP);
    float4v acc[16];
    #pragma unroll
    for (int n = 0; n < 16; ++n) acc[n] = (float4v){0.f, 0.f, 0.f, 0.f};
    float sq = 0.f;
    #pragma unroll
    for (int s = 0; s < 4; ++s) {
        short8v af;
        if (bf) {
            af = ((const short8v*)x)[(size_t)jac * 16 + s * 4 + grp];
            #pragma unroll
            for (int i = 0; i < 8; ++i) { float v = bs2f(af[i]); sq = fmaf(v, v, sq); }
        } else {
            const float* er = (const float*)x + (size_t)jac * 128 + s * 32 + grp * 8;
            float4v lo = *(const float4v*)er;
            float4v hi = *(const float4v*)(er + 4);
            float xv[8] = {lo[0], lo[1], lo[2], lo[3], hi[0], hi[1], hi[2], hi[3]};
            #pragma unroll
            for (int i = 0; i < 8; ++i) { sq = fmaf(xv[i], xv[i], sq); af[i] = f2bs(xv[i]); }
        }
        #pragma unroll
        for (int n = 0; n < 16; ++n) {
            acc[n] = __builtin_amdgcn_mfma_f32_16x16x32_bf16(af, WP[(s * 16 + n) * 64 + l], acc[n], 0, 0, 0);
        }
    }
    sq += __shfl_xor(sq, 16, 64);
    sq += __shfl_xor(sq, 32, 64);
    if (grp == 0 && ja < N) ws[OFF_XN + ja] = sqrtf(sq);
    bf16* XA = (bf16*)(ws + OFF_A);
    #pragma unroll
    for (int reg = 0; reg < 4; ++reg) {
        int jd = n0 + grp * 4 + reg;
        if (jd >= N) continue;
        #pragma unroll
        for (int n = 0; n < 16; ++n) {
            int c = n * 16 + row;
            if (n < 8) {
                XA[(size_t)jd * 128 + c] = __float2bfloat16(acc[n][reg] + ldf(b_e, c, bf));
            } else {
                XA[NB + (size_t)jd * 128 + (c - 128)] = __float2bfloat16(acc[n][reg]);
            }
        }
    }
}

// Per-edge MLP via MFMA, operand-swapped (D[ch][edge]): lane owns one edge
// (eq = l&15) x 32 channels (ch = m*16 + grp*4 + w).
//   pre = XA[r] + XB[cd] + ea @ W3;  e = LN(relu(pre)) * g + b + ea
// The "+ea" residual values are extracted from the retained B-fragments via
// 64-bit shuffles (no ea re-read): lane (eq,grp) needs cols m*16+grp*4+{0..3}
// = the (grp&1)-half of the fragment held by lane eq+32*(m&1)+16*(grp>>1).
__global__ __launch_bounds__(256) void k_edge1_mfma(const void* __restrict__ ea,
                                                    const int* __restrict__ ei,
                                                    const void* __restrict__ g_e,
                                                    const void* __restrict__ be_e,
                                                    float* __restrict__ ws,
                                                    void* __restrict__ d_out) {
    int bf = get_flag(ws);
    void* eo = e_base(d_out, bf);
    int l = threadIdx.x & 63;
    int wv = threadIdx.x >> 6;
    int e0w = blockIdx.x * 64 + wv * 16;
    if (e0w >= E) return;
    int eq = l & 15, grp = l >> 4;

    int j = e0w + eq;
    bool valid = j < E;
    int jc = valid ? j : E - 1;
    int r = ei[jc], cd = ei[E + jc];

    // ---- prefetch epilogue gathers (independent of GEMM) ----
    const bf16* XAp = (const bf16*)(ws + OFF_A);
    short4v xa[8], xb[8];
    #pragma unroll
    for (int m = 0; m < 8; ++m) {
        int ch = m * 16 + grp * 4;
        xa[m] = *(const short4v*)(XAp + (size_t)r * 128 + ch);
        xb[m] = *(const short4v*)(XAp + NB + (size_t)cd * 128 + ch);
    }

    // ---- GEMM: acc[m] = W3_frag(A) x ea_frag(B) -> D[ch][edge] ----
    const short8v* WB = (const short8v*)(ws + OFF_WB);
    union { short8v v; u64 q[2]; } bfr[4];
    #pragma unroll
    for (int s = 0; s < 4; ++s) {
        if (bf) {
            bfr[s].v = ((const short8v*)ea)[(size_t)jc * 16 + s * 4 + grp];
        } else {
            const float* er = (const float*)ea + (size_t)jc * 128 + s * 32 + grp * 8;
            float4v lo = *(const float4v*)er;
            float4v hi = *(const float4v*)(er + 4);
            short8v t;
            t[0] = f2bs(lo[0]); t[1] = f2bs(lo[1]); t[2] = f2bs(lo[2]); t[3] = f2bs(lo[3]);
            t[4] = f2bs(hi[0]); t[5] = f2bs(hi[1]); t[6] = f2bs(hi[2]); t[7] = f2bs(hi[3]);
            bfr[s].v = t;
        }
    }
    float4v acc[8];
    #pragma unroll
    for (int m = 0; m < 8; ++m) acc[m] = (float4v){0.f, 0.f, 0.f, 0.f};
    #pragma unroll
    for (int s = 0; s < 4; ++s) {
        #pragma unroll
        for (int m = 0; m < 8; ++m) {
            acc[m] = __builtin_amdgcn_mfma_f32_16x16x32_bf16(WB[(s * 8 + m) * 64 + l], bfr[s].v, acc[m], 0, 0, 0);
        }
    }

    // ---- epilogue ----
    float p[8][4];
    float s1 = 0.f, s2 = 0.f;
    #pragma unroll
    for (int m = 0; m < 8; ++m) {
        #pragma unroll
        for (int w = 0; w < 4; ++w) {
            float v = acc[m][w] + bs2f(xa[m][w]) + bs2f(xb[m][w]);
            v = fmaxf(v, 0.f);
            p[m][w] = v;
            s1 += v;
            s2 = fmaf(v, v, s2);
        }
    }
    // eav extraction: 2 x u64 shuffle + select per m
    u64 eavq[8];
    #pragma unroll
    for (int m = 0; m < 8; ++m) {
        const int s = m >> 1;
        int srcl = eq + 32 * (m & 1) + 16 * (grp >> 1);
        u64 a = __shfl(bfr[s].q[0], srcl, 64);
        u64 b = __shfl(bfr[s].q[1], srcl, 64);
        eavq[m] = (grp & 1) ? b : a;
    }
    s1 += __shfl_xor(s1, 16, 64);
    s1 += __shfl_xor(s1, 32, 64);
    s2 += __shfl_xor(s2, 16, 64);
    s2 += __shfl_xor(s2, 32, 64);
    float mu = s1 * (1.f / 128.f);
    float var = s2 * (1.f / 128.f) - mu * mu;
    float rstd = rsqrtf(fmaxf(var, 0.f) + 1e-5f);

    #pragma unroll
    for (int m = 0; m < 8; ++m) {
        int ch = m * 16 + grp * 4;
        float4v gg = load4(g_e, ch, bf);
        float4v bb = load4(be_e, ch, bf);
        float4v ev;
        #pragma unroll
        for (int w = 0; w < 4; ++w) {
            float eav = bs2f((short)(eavq[m] >> (16 * w)));
            ev[w] = (p[m][w] - mu) * rstd * gg[w] + bb[w] + eav;
        }
        if (valid) store4(eo, (size_t)j * 128 + ch, ev, bf);   // regular store: agg re-reads from L2/L3
    }
}

// Exclusive scan of degree counts -> CSR offsets + scatter cursors. 1 block.
__global__ __launch_bounds__(256) void k_scan(float* __restrict__ ws) {
    const int* deg = (const int*)(ws + OFF_DEG);
    int* offs = (int*)(ws + OFF_OFFS);
    int* cur  = (int*)(ws + OFF_CUR);
    __shared__ int sums[256];
    __shared__ int carry[257];
    int t = threadIdx.x;
    const int chunk = (N + 255) / 256;
    int lo = t * chunk, hi = lo + chunk < N ? lo + chunk : N;
    int s = 0;
    for (int i = lo; i < hi; ++i) s += deg[i];
    sums[t] = s;
    __syncthreads();
    if (t == 0) {
        int acc = 0;
        #pragma unroll 4
        for (int i = 0; i < 256; ++i) { carry[i] = acc; acc += sums[i]; }
        carry[256] = acc;
    }
    __syncthreads();
    int acc = carry[t];
    for (int i = lo; i < hi; ++i) { offs[i] = acc; cur[i] = acc; acc += deg[i]; }
    if (t == 0) offs[N] = carry[256];
}

// Scatter edge ids into CSR list by destination.
__global__ void k_scatter(const int* __restrict__ ei, float* __restrict__ ws) {
    int j = blockIdx.x * blockDim.x + threadIdx.x;
    if (j >= E) return;
    int cd = ei[E + j];
    int pos = atomicAdd((int*)(ws + OFF_CUR) + cd, 1);
    ((int*)(ws + OFF_LIST))[pos] = j;
}

// Per node: gather e rows (L2/L3-resident, just written) + x rows via LIST,
// recompute msg = relu(x[r]+e)+eps, softmax-aggregate (fixed-shift exp;
// shift-invariant, 0 <= msg*t <~ 22). out = agg + x -> OUT bf16.
// 16-edge-parallel x 8-channel vector loads.
__global__ __launch_bounds__(256) void k_agg(const void* __restrict__ x,
                                             const int* __restrict__ ei,
                                             const void* __restrict__ t_p,
                                             void* __restrict__ d_out,
                                             float* __restrict__ ws) {
    int bf = get_flag(ws);
    const void* e_in = e_base(d_out, bf);
    int n = blockIdx.x, tid = threadIdx.x;
    int par = tid >> 4;          // 0..15 edge-parallel
    int cg = tid & 15;           // channel group: ch = cg*8 .. +8
    const int* offs = (const int*)(ws + OFF_OFFS);
    const int* list = (const int*)(ws + OFF_LIST);
    int s0 = offs[n], s1v = offs[n + 1];
    float t = lds_scalar(t_p, bf);
    float den[8], num[8];
    #pragma unroll
    for (int w = 0; w < 8; ++w) { den[w] = 0.f; num[w] = 0.f; }
    for (int i = s0 + par; i < s1v; i += 16) {
        int jj = list[i];
        int r = ei[jj];
        float4v e0 = load4(e_in, (size_t)jj * 128 + cg * 8, bf);
        float4v e1 = load4(e_in, (size_t)jj * 128 + cg * 8 + 4, bf);
        float4v x0 = load4(x, (size_t)r * 128 + cg * 8, bf);
        float4v x1 = load4(x, (size_t)r * 128 + cg * 8 + 4, bf);
        #pragma unroll
        for (int w = 0; w < 8; ++w) {
            float ev = w < 4 ? e0[w & 3] : e1[w & 3];
            float xv = w < 4 ? x0[w & 3] : x1[w & 3];
            float m = fmaxf(xv + ev, 0.f) + 1e-7f;
            float ex = __expf(fmaf(m, t, -15.0f));
            den[w] += ex;
            num[w] = fmaf(m, ex, num[w]);
        }
    }
    __shared__ float sd[16][132];
    __shared__ float sn[16][132];
    #pragma unroll
    for (int w = 0; w < 8; ++w) { sd[par][cg * 8 + w] = den[w]; sn[par][cg * 8 + w] = num[w]; }
    __syncthreads();
    if (tid < 128) {
        float dn = 0.f, nm = 0.f;
        #pragma unroll
        for (int p = 0; p < 16; ++p) { dn += sd[p][tid]; nm += sn[p][tid]; }
        float ag = dn > 0.f ? nm / dn : 0.f;
        float out = ag + ldf(x, (size_t)n * 128 + tid, bf);
        ((bf16*)(ws + OFF_OUT))[(size_t)n * 128 + tid] = __float2bfloat16(out);
    }
}

// H1 = out @ W_m1 + b_m1 (bf16, N x 256), 64 nodes per block,
// with FUSED BatchNorm column sums/sumsq (shfl + LDS + global atomics).
// No early returns: all waves reach the barrier.
__global__ __launch_bounds__(256) void k_h1_mfma(const void* __restrict__ b_m1,
                                                 float* __restrict__ ws) {
    int bf = get_flag(ws);
    int l = threadIdx.x & 63, wv = threadIdx.x >> 6;
    int n0 = blockIdx.x * 64 + wv * 16;
    int row = l & 15, grp = l >> 4;
    int ja = n0 + row;
    int jac = ja < N ? ja : N - 1;
    const short8v* OUT = (const short8v*)(ws + OFF_OUT);
    const short8v* M1 = (const short8v*)(ws + OFF_WM1P);
    float4v acc[16];
    #pragma unroll
    for (int n = 0; n < 16; ++n) acc[n] = (float4v){0.f, 0.f, 0.f, 0.f};
    #pragma unroll
    for (int s = 0; s < 4; ++s) {
        short8v af = OUT[(size_t)jac * 16 + s * 4 + grp];
        #pragma unroll
        for (int n = 0; n < 16; ++n) {
            acc[n] = __builtin_amdgcn_mfma_f32_16x16x32_bf16(af, M1[(s * 16 + n) * 64 + l], acc[n], 0, 0, 0);
        }
    }
    __shared__ float sds[4][264];
    __shared__ float sqs[4][264];
    bf16* H1 = (bf16*)(ws + OFF_A);
    #pragma unroll
    for (int n = 0; n < 16; ++n) {
        int col = n * 16 + row;
        float bias = ldf(b_m1, col, bf);
        float vs = 0.f, vq = 0.f;
        #pragma unroll
        for (int reg = 0; reg < 4; ++reg) {
            int jd = n0 + grp * 4 + reg;
            float v = acc[n][reg] + bias;
            if (jd < N) {
                H1[(size_t)jd * 256 + col] = __float2bfloat16(v);
                vs += v;
                vq = fmaf(v, v, vq);
            }
        }
        vs += __shfl_xor(vs, 16, 64); vs += __shfl_xor(vs, 32, 64);
        vq += __shfl_xor(vq, 16, 64); vq += __shfl_xor(vq, 32, 64);
        if (grp == 0) { sds[wv][col] = vs; sqs[wv][col] = vq; }
    }
    __syncthreads();
    int t = threadIdx.x;
    if (t < 256) {
        float s = sds[0][t] + sds[1][t] + sds[2][t] + sds[3][t];
        float q = sqs[0][t] + sqs[1][t] + sqs[2][t] + sqs[3][t];
        atomicAdd(&ws[OFF_BNS + t], s);
        atomicAdd(&ws[OFF_BNQ + t], q);
    }
}

// Per 64 nodes: hbn = relu(BN(H1)) built in-register as A-fragment;
// h = hbn @ W_m2 + b_m2; MessageNorm; residual + LayerNorm -> x_out.
__global__ __launch_bounds__(256) void k_node_post_mfma(const void* __restrict__ x,
                                                        const void* __restrict__ g_bn,
                                                        const void* __restrict__ b_bn,
                                                        const void* __restrict__ b_m2,
                                                        const void* __restrict__ scale_p,
                                                        const void* __restrict__ g_n,
                                                        const void* __restrict__ b_n,
                                                        float* __restrict__ ws,
                                                        void* __restrict__ x_out) {
    int bf = get_flag(ws);
    __shared__ float sA[256];   // per-col BN scale = rstd*g
    __shared__ float sB[256];   // per-col BN shift = b - mu*rstd*g
    {
        int t = threadIdx.x;
        const float inv_n = 1.f / (float)N;
        float mu = ws[OFF_BNS + t] * inv_n;
        float var = ws[OFF_BNQ + t] * inv_n - mu * mu;
        float rs = rsqrtf(fmaxf(var, 0.f) + 1e-5f) * ldf(g_bn, t, bf);
        sA[t] = rs;
        sB[t] = ldf(b_bn, t, bf) - mu * rs;
    }
    __syncthreads();
    int l = threadIdx.x & 63, wv = threadIdx.x >> 6;
    int n0 = blockIdx.x * 64 + wv * 16;
    if (n0 >= N) return;   // after the only barrier — safe
    int row = l & 15, grp = l >> 4;
    int ja = n0 + row;
    int jac = ja < N ? ja : N - 1;
    const short8v* H1 = (const short8v*)(ws + OFF_A);
    const short8v* M2 = (const short8v*)(ws + OFF_WM2P);
    float4v acc[8];
    #pragma unroll
    for (int n = 0; n < 8; ++n) acc[n] = (float4v){0.f, 0.f, 0.f, 0.f};
    #pragma unroll
    for (int s = 0; s < 8; ++s) {
        short8v hv = H1[(size_t)jac * 32 + s * 4 + grp];
        int kb = s * 32 + grp * 8;
        short8v af;
        #pragma unroll
        for (int i = 0; i < 8; ++i) {
            float v = fmaf(bs2f(hv[i]), sA[kb + i], sB[kb + i]);
            af[i] = f2bs(fmaxf(v, 0.f));
        }
        #pragma unroll
        for (int n = 0; n < 8; ++n) {
            acc[n] = __builtin_amdgcn_mfma_f32_16x16x32_bf16(af, M2[(s * 8 + n) * 64 + l], acc[n], 0, 0, 0);
        }
    }
    float scl = lds_scalar(scale_p, bf);
    #pragma unroll
    for (int reg = 0; reg < 4; ++reg) {
        int jd = n0 + grp * 4 + reg;
        int jdc = jd < N ? jd : N - 1;
        float h[8];
        float ss = 0.f;
        #pragma unroll
        for (int n = 0; n < 8; ++n) {
            h[n] = acc[n][reg] + ldf(b_m2, n * 16 + row, bf);
            ss = fmaf(h[n], h[n], ss);
        }
        #pragma unroll
        for (int off = 1; off < 16; off <<= 1) ss += __shfl_xor(ss, off, 64);
        float hs = ws[OFF_XN + jdc] * scl / fmaxf(sqrtf(ss), 1e-12f);
        float y[8];
        float s1 = 0.f;
        #pragma unroll
        for (int n = 0; n < 8; ++n) {
            y[n] = ldf(x, (size_t)jdc * 128 + n * 16 + row, bf) + h[n] * hs;
            s1 += y[n];
        }
        #pragma unroll
        for (int off = 1; off < 16; off <<= 1) s1 += __shfl_xor(s1, off, 64);
        float mu = s1 * (1.f / 128.f);
        float s2 = 0.f;
        #pragma unroll
        for (int n = 0; n < 8; ++n) { float d = y[n] - mu; s2 = fmaf(d, d, s2); }
        #pragma unroll
        for (int off = 1; off < 16; off <<= 1) s2 += __shfl_xor(s2, off, 64);
        float rstd = rsqrtf(s2 * (1.f / 128.f) + 1e-5f);
        if (jd < N) {
            #pragma unroll
            for (int n = 0; n < 8; ++n) {
                int col = n * 16 + row;
                float o = (y[n] - mu) * rstd * ldf(g_n, col, bf) + ldf(b_n, col, bf);
                stf_nt(x_out, (size_t)jd * 128 + col, o, bf);
            }
        }
    }
}

// ---------------- launcher ----------------

extern "C" void kernel_launch(void* const* d_in, const int* in_sizes, int n_in,
                              void* d_out, int out_size, void* d_ws, size_t ws_size,
                              hipStream_t stream) {
    const void* x    = d_in[0];
    const void* ea   = d_in[1];
    const int*  ei   = (const int*)d_in[2];
    const void* W_e  = d_in[3];
    const void* b_e  = d_in[4];
    const void* g_e  = d_in[5];
    const void* be_e = d_in[6];
    const void* t_p  = d_in[7];
    const void* W_m1 = d_in[8];
    const void* b_m1 = d_in[9];
    const void* g_bn = d_in[10];
    const void* b_bn = d_in[11];
    const void* W_m2 = d_in[12];
    const void* b_m2 = d_in[13];
    const void* scl  = d_in[14];
    const void* g_n  = d_in[15];
    const void* b_n  = d_in[16];

    float* ws = (float*)d_ws;

    k_detect<<<1, 256, 0, stream>>>((const unsigned short*)x, ws);
    k_init<<<512, 256, 0, stream>>>(ws, W_e, W_m1, W_m2, ei);
    k_scan<<<1, 256, 0, stream>>>(ws);
    k_scatter<<<(E + 255) / 256, 256, 0, stream>>>(ei, ws);
    k_node_pre_mfma<<<NBLK, 256, 0, stream>>>(x, b_e, ws);
    k_edge1_mfma<<<(E + 63) / 64, 256, 0, stream>>>(ea, ei, g_e, be_e, ws, d_out);
    k_agg<<<N, 256, 0, stream>>>(x, ei, t_p, d_out, ws);
    k_h1_mfma<<<NBLK, 256, 0, stream>>>(b_m1, ws);
    k_node_post_mfma<<<NBLK, 256, 0, stream>>>(x, g_bn, b_bn, b_m2, scl, g_n, b_n, ws, d_out);
}